// Round 4
// baseline (569.121 us; speedup 1.0000x reference)
//
#include <hip/hip_runtime.h>

#define N_NODES 50000
#define N_EDGES 800000
#define HEADS 8
#define FOUT 32
#define HF 256   // HEADS*FOUT
#define IN_F 256
#define EDGE_F 64

typedef __attribute__((ext_vector_type(8))) short bf16x8;
typedef __attribute__((ext_vector_type(4))) float f32x4;

__device__ inline ushort f2bf(float f) {  // round-to-nearest-even f32 -> bf16
  unsigned u = __float_as_uint(f);
  unsigned r = 0x7FFFu + ((u >> 16) & 1u);
  return (ushort)((u + r) >> 16);
}

// ---------------- convert + transpose W: Wt[n][k] = bf16(W[k][n]) ----------------
__global__ __launch_bounds__(256) void k_cvtW(const float* __restrict__ W,
                                              ushort* __restrict__ Wt)
{
  int i = blockIdx.x * 256 + threadIdx.x;   // output index, coalesced write
  int n = i >> 8, k = i & 255;
  Wt[i] = f2bf(W[k * HF + n]);
}

// ---------------- fused GEMM: Whb = bf16(h @ W), alpha_s/d from f32 accs ----------------
// Block: 64 rows x 256 cols, 4 waves; wave w owns cols [64w,64w+64) = heads {2w,2w+1}.
__global__ __launch_bounds__(256) void k_gemm_fused(
    const float* __restrict__ A,     // h [M][256] f32
    const ushort* __restrict__ Wt,   // [256 n][256 k] bf16, K-contig
    const float* __restrict__ a_src, const float* __restrict__ a_dst,
    ushort* __restrict__ Whb,        // [M][256] bf16
    float* __restrict__ alpha_s, float* __restrict__ alpha_d, int M)
{
  __shared__ ushort As[64 * 40];    // stride 40 bf16 (80B): 2-way (free) bank aliasing
  __shared__ ushort Bs[256 * 40];
  const int tid = threadIdx.x;
  const int wave = tid >> 6, lane = tid & 63;
  const int m0 = blockIdx.x * 64;
  const int row16 = lane & 15;
  const int kg = lane >> 4;        // k-group 0..3 -> k offset kg*8
  f32x4 acc[4][4] = {};

  const int a_r = tid >> 2;              // 0..63
  const int a_c = (tid & 3) * 8;         // bf16 col 0,8,16,24
  const int a_row = m0 + a_r;

  for (int k0 = 0; k0 < IN_F; k0 += 32) {
    // A staging: 8 f32 -> 8 bf16 per thread
    uint4 av = make_uint4(0, 0, 0, 0);
    if (a_row < M) {
      float4 f0 = *(const float4*)&A[(size_t)a_row * IN_F + k0 + a_c];
      float4 f1 = *(const float4*)&A[(size_t)a_row * IN_F + k0 + a_c + 4];
      av.x = (unsigned)f2bf(f0.x) | ((unsigned)f2bf(f0.y) << 16);
      av.y = (unsigned)f2bf(f0.z) | ((unsigned)f2bf(f0.w) << 16);
      av.z = (unsigned)f2bf(f1.x) | ((unsigned)f2bf(f1.y) << 16);
      av.w = (unsigned)f2bf(f1.z) | ((unsigned)f2bf(f1.w) << 16);
    }
    *(uint4*)&As[a_r * 40 + a_c] = av;
    const uint4* bp = (const uint4*)&Wt[(size_t)tid * IN_F + k0];
    uint4 b0 = bp[0], b1 = bp[1];
    *(uint4*)&Bs[tid * 40 + 0] = b0;
    *(uint4*)&Bs[tid * 40 + 8] = b1;
    uint4 b2 = bp[2], b3 = bp[3];
    *(uint4*)&Bs[tid * 40 + 16] = b2;
    *(uint4*)&Bs[tid * 40 + 24] = b3;
    __syncthreads();
    bf16x8 af[4], bfr[4];
#pragma unroll
    for (int mi = 0; mi < 4; ++mi)
      af[mi] = *(const bf16x8*)&As[(mi * 16 + row16) * 40 + kg * 8];
#pragma unroll
    for (int ni = 0; ni < 4; ++ni)
      bfr[ni] = *(const bf16x8*)&Bs[(wave * 64 + ni * 16 + row16) * 40 + kg * 8];
#pragma unroll
    for (int mi = 0; mi < 4; ++mi)
#pragma unroll
      for (int ni = 0; ni < 4; ++ni)
        acc[mi][ni] = __builtin_amdgcn_mfma_f32_16x16x32_bf16(af[mi], bfr[ni], acc[mi][ni], 0, 0, 0);
    __syncthreads();
  }

  // epilogue 1: alpha coefficients for this wave's two heads
  float cs[4], cd[4];
#pragma unroll
  for (int ni = 0; ni < 4; ++ni) {
    int hh = 2 * wave + (ni >> 1);
    int ff = (ni & 1) * 16 + row16;
    cs[ni] = a_src[hh * FOUT + ff];
    cd[ni] = a_dst[hh * FOUT + ff];
  }
  // C/D layout (m89-verified): col = lane&15 (row16), row = kg*4 + reg
#pragma unroll
  for (int mi = 0; mi < 4; ++mi) {
#pragma unroll
    for (int r = 0; r < 4; ++r) {
      int row = m0 + mi * 16 + kg * 4 + r;
      float ps0 = acc[mi][0][r] * cs[0] + acc[mi][1][r] * cs[1];
      float ps1 = acc[mi][2][r] * cs[2] + acc[mi][3][r] * cs[3];
      float pd0 = acc[mi][0][r] * cd[0] + acc[mi][1][r] * cd[1];
      float pd1 = acc[mi][2][r] * cd[2] + acc[mi][3][r] * cd[3];
#pragma unroll
      for (int msk = 1; msk <= 8; msk <<= 1) {
        ps0 += __shfl_xor(ps0, msk, 64);
        ps1 += __shfl_xor(ps1, msk, 64);
        pd0 += __shfl_xor(pd0, msk, 64);
        pd1 += __shfl_xor(pd1, msk, 64);
      }
      if (row16 == 0 && row < M) {
        *(float2*)&alpha_s[row * 8 + 2 * wave] = make_float2(ps0, ps1);
        *(float2*)&alpha_d[row * 8 + 2 * wave] = make_float2(pd0, pd1);
      }
      // epilogue 2: bf16 store of this row's 64 cols owned by the wave
      if (row < M) {
#pragma unroll
        for (int ni = 0; ni < 4; ++ni)
          Whb[(size_t)row * HF + wave * 64 + ni * 16 + row16] = f2bf(acc[mi][ni][r]);
      }
    }
  }
}

// ---------------- B[k,h] = sum_f We_w[k, h*32+f] * a_edge[h,f]  (64x8) ----------------
__global__ __launch_bounds__(256) void k_bmat(
    const float* __restrict__ We_w, const float* __restrict__ a_edge,
    float* __restrict__ Bmat)
{
  int i = blockIdx.x * 256 + threadIdx.x;
  if (i >= EDGE_F * HEADS) return;
  int k = i >> 3, h = i & 7;
  float s = 0.f;
#pragma unroll
  for (int f = 0; f < FOUT; ++f)
    s += We_w[k * HF + h * FOUT + f] * a_edge[h * FOUT + f];
  Bmat[i] = s;   // layout [k][h]
}

// ---------------- degree histogram ----------------
__global__ __launch_bounds__(256) void k_hist(const int* __restrict__ dst,
                                              int* __restrict__ deg)
{
  int e = blockIdx.x * 256 + threadIdx.x;
  if (e < N_EDGES) atomicAdd(&deg[dst[e]], 1);
}

// ---------------- exclusive scan: thread-serial chunks + one block scan ----------------
#define SCAN_ITEMS 49   // 1024*49 = 50176 >= N_NODES
__global__ __launch_bounds__(1024) void k_scan(const int* __restrict__ deg,
                                               int* __restrict__ offsets,
                                               int* __restrict__ cursor)
{
  __shared__ int sums[1024];
  int t = threadIdx.x;
  int base = t * SCAN_ITEMS;
  int s = 0;
  for (int i = 0; i < SCAN_ITEMS; ++i) {
    int idx = base + i;
    if (idx < N_NODES) s += deg[idx];
  }
  sums[t] = s;
  __syncthreads();
  int x = s;
  for (int off = 1; off < 1024; off <<= 1) {
    int y = (t >= off) ? sums[t - off] : 0;
    __syncthreads();
    x += y;
    sums[t] = x;
    __syncthreads();
  }
  int run = x - s;   // exclusive prefix of this thread's chunk
  for (int i = 0; i < SCAN_ITEMS; ++i) {
    int idx = base + i;
    if (idx < N_NODES) {
      offsets[idx] = run;
      cursor[idx] = run;
      run += deg[idx];
    }
  }
  if (t == 1023) offsets[N_NODES] = x;
}

// ---------------- edge logits + leaky relu, scattered into dst-sorted order ----------------
__global__ __launch_bounds__(256) void k_logits(
    const float* __restrict__ ef, const int* __restrict__ src,
    const int* __restrict__ dst, const float* __restrict__ alpha_s,
    const float* __restrict__ alpha_d, const float* __restrict__ Bmat,
    int* __restrict__ cursor, float* __restrict__ s_sorted,
    int* __restrict__ src_srt)
{
  __shared__ float Bs[EDGE_F * HEADS];
  for (int i = threadIdx.x; i < EDGE_F * HEADS; i += 256) Bs[i] = Bmat[i];
  __syncthreads();
  int e = blockIdx.x * 256 + threadIdx.x;
  if (e >= N_EDGES) return;
  int sn = src[e], dn = dst[e];
  float sc[8];
  {
    const float4* a1 = (const float4*)&alpha_s[sn * 8];
    const float4* a2 = (const float4*)&alpha_d[dn * 8];
    float4 p = a1[0], q = a1[1], r = a2[0], w = a2[1];
    sc[0] = p.x + r.x; sc[1] = p.y + r.y; sc[2] = p.z + r.z; sc[3] = p.w + r.w;
    sc[4] = q.x + w.x; sc[5] = q.y + w.y; sc[6] = q.z + w.z; sc[7] = q.w + w.w;
  }
  const f32x4* efr = (const f32x4*)&ef[(size_t)e * EDGE_F];
  for (int g = 0; g < EDGE_F / 4; ++g) {
    f32x4 v = __builtin_nontemporal_load(&efr[g]);   // streamed once: don't pollute L2
    const float* b0 = &Bs[(g * 4) * 8];
#pragma unroll
    for (int hh = 0; hh < 8; ++hh)
      sc[hh] += v.x * b0[hh] + v.y * b0[8 + hh] + v.z * b0[16 + hh] + v.w * b0[24 + hh];
  }
#pragma unroll
  for (int hh = 0; hh < 8; ++hh)
    sc[hh] = sc[hh] > 0.f ? sc[hh] : 0.01f * sc[hh];
  int p = atomicAdd(&cursor[dn], 1);
  float4* o = (float4*)&s_sorted[p * 8];
  o[0] = make_float4(sc[0], sc[1], sc[2], sc[3]);
  o[1] = make_float4(sc[4], sc[5], sc[6], sc[7]);
  src_srt[p] = sn;
}

// ---------------- per-node segment softmax + bf16 pair-packed gather-sum + ELU ----------------
__global__ __launch_bounds__(256) void k_agg(
    const float* __restrict__ s_sorted, const int* __restrict__ src_srt,
    const int* __restrict__ offsets, const uint* __restrict__ Whb_u,  // [N][128] uint = 2x bf16
    float* __restrict__ out)
{
  int n = blockIdx.x;
  int beg = offsets[n], end = offsets[n + 1];
  int t = threadIdx.x;
  int h = t >> 5;       // head (pass A/B mapping)
  int j = t & 31;       // lane-in-head / edge slot
  const int p = t & 127;    // bf16-pair index: cols {2p, 2p+1}
  const int g = t >> 7;     // edge parity group
  const int hp = p >> 4;    // head of pair p
  __shared__ float mh[HEADS], dh[HEADS];
  __shared__ int s_idx[32];
  __shared__ float s_w[32 * 8];   // [edge][head]
  __shared__ float s_red[256];

  // pass A: per-head max over incoming edges
  float m = -3.0e38f;
  for (int i = beg + j; i < end; i += 32)
    m = fmaxf(m, s_sorted[i * 8 + h]);
#pragma unroll
  for (int off = 16; off > 0; off >>= 1)
    m = fmaxf(m, __shfl_xor(m, off, 32));
  if (j == 0) mh[h] = m;
  __syncthreads();
  float mx = mh[h];

  // pass B: per-head denominator
  float d = 0.f;
  for (int i = beg + j; i < end; i += 32)
    d += __expf(s_sorted[i * 8 + h] - mx);
#pragma unroll
  for (int off = 16; off > 0; off >>= 1)
    d += __shfl_xor(d, off, 32);
  if (j == 0) dh[h] = (d > 0.f) ? 1.0f / d : 0.f;
  __syncthreads();
  float inv = dh[h];

  // pass C: chunks of 32 edges; weights once into LDS; bf16 pair gather, 2 edges in flight
  float acc0 = 0.f, acc1 = 0.f;
  for (int c0 = beg; c0 < end; c0 += 32) {
    int cnt = end - c0; cnt = cnt < 32 ? cnt : 32;
    if (t < cnt) s_idx[t] = src_srt[c0 + t];
    if (j < cnt) s_w[j * 8 + h] = __expf(s_sorted[(c0 + j) * 8 + h] - mx) * inv;
    __syncthreads();
    for (int k = g; k < cnt; k += 2) {
      uint wv = Whb_u[(size_t)s_idx[k] * 128 + p];
      float wt = s_w[k * 8 + hp];
      acc0 = fmaf(wt, __uint_as_float(wv << 16), acc0);
      acc1 = fmaf(wt, __uint_as_float(wv & 0xFFFF0000u), acc1);
    }
    __syncthreads();
  }
  // combine the two edge-parity groups, fused ELU, coalesced float2 store
  if (g) { s_red[p * 2] = acc0; s_red[p * 2 + 1] = acc1; }
  __syncthreads();
  if (!g) {
    acc0 += s_red[p * 2];
    acc1 += s_red[p * 2 + 1];
    float2 o;
    o.x = acc0 > 0.f ? acc0 : expm1f(acc0);
    o.y = acc1 > 0.f ? acc1 : expm1f(acc1);
    *(float2*)&out[(size_t)n * HF + p * 2] = o;
  }
}

extern "C" void kernel_launch(void* const* d_in, const int* in_sizes, int n_in,
                              void* d_out, int out_size, void* d_ws, size_t ws_size,
                              hipStream_t stream)
{
  const float* h    = (const float*)d_in[0];
  const float* ef   = (const float*)d_in[1];
  const int*   src  = (const int*)d_in[2];
  const int*   dst  = (const int*)d_in[3];
  const float* W_w  = (const float*)d_in[4];
  const float* We_w = (const float*)d_in[5];
  const float* a_s  = (const float*)d_in[6];
  const float* a_d  = (const float*)d_in[7];
  const float* a_e  = (const float*)d_in[8];
  float* out = (float*)d_out;

  char* ws = (char*)d_ws;
  size_t off = 0;
  auto take = [&](size_t bytes) {
    char* p = ws + off;
    off += (bytes + 255) & ~(size_t)255;
    return p;
  };
  ushort* Whb     = (ushort*)take((size_t)N_NODES * HF * 2);         // 25.6 MB bf16
  float* s_sorted = (float*)take((size_t)N_EDGES * HEADS * 4);       // 25.6 MB
  float* alpha_s  = (float*)take((size_t)N_NODES * HEADS * 4);
  float* alpha_d  = (float*)take((size_t)N_NODES * HEADS * 4);
  int*   src_srt  = (int*)take((size_t)N_EDGES * 4);
  int*   deg      = (int*)take((size_t)N_NODES * 4);
  int*   offs     = (int*)take((size_t)(N_NODES + 1) * 4);
  int*   cursor   = (int*)take((size_t)N_NODES * 4);
  float* Bmat     = (float*)take((size_t)EDGE_F * HEADS * 4);
  ushort* Wt      = (ushort*)take((size_t)HF * IN_F * 2);            // 128 KB

  (void)hipMemsetAsync(deg, 0, N_NODES * sizeof(int), stream);
  k_hist<<<(N_EDGES + 255) / 256, 256, 0, stream>>>(dst, deg);
  k_scan<<<1, 1024, 0, stream>>>(deg, offs, cursor);
  k_bmat<<<(EDGE_F * HEADS + 255) / 256, 256, 0, stream>>>(We_w, a_e, Bmat);
  k_cvtW<<<(HF * IN_F) / 256, 256, 0, stream>>>(W_w, Wt);
  k_gemm_fused<<<(N_NODES + 63) / 64, 256, 0, stream>>>(h, Wt, a_s, a_d, Whb,
                                                        alpha_s, alpha_d, N_NODES);
  k_logits<<<(N_EDGES + 255) / 256, 256, 0, stream>>>(ef, src, dst, alpha_s, alpha_d,
                                                      Bmat, cursor, s_sorted, src_srt);
  k_agg<<<N_NODES, 256, 0, stream>>>(s_sorted, src_srt, offs, (const uint*)Whb, out);
}

// Round 5
// 463.804 us; speedup vs baseline: 1.2271x; 1.2271x over previous
//
#include <hip/hip_runtime.h>

#define N_NODES 50000
#define N_EDGES 800000
#define HEADS 8
#define FOUT 32
#define HF 256   // HEADS*FOUT
#define IN_F 256
#define EDGE_F 64

typedef __attribute__((ext_vector_type(8))) short bf16x8;
typedef __attribute__((ext_vector_type(4))) float f32x4;

__device__ inline ushort f2bf(float f) {  // round-to-nearest-even f32 -> bf16
  unsigned u = __float_as_uint(f);
  unsigned r = 0x7FFFu + ((u >> 16) & 1u);
  return (ushort)((u + r) >> 16);
}

// ---------------- convert + transpose W: Wt[n][k] = bf16(W[k][n]) ----------------
__global__ __launch_bounds__(256) void k_cvtW(const float* __restrict__ W,
                                              ushort* __restrict__ Wt)
{
  int i = blockIdx.x * 256 + threadIdx.x;   // output index, coalesced write
  int n = i >> 8, k = i & 255;
  Wt[i] = f2bf(W[k * HF + n]);
}

// ---------------- fused GEMM: Whb = bf16(h @ W), alpha_s/d from f32 accs ----------------
// Block: 64 rows x 256 cols, 4 waves; wave w owns cols [64w,64w+64) = heads {2w,2w+1}.
__global__ __launch_bounds__(256) void k_gemm_fused(
    const float* __restrict__ A,     // h [M][256] f32
    const ushort* __restrict__ Wt,   // [256 n][256 k] bf16, K-contig
    const float* __restrict__ a_src, const float* __restrict__ a_dst,
    ushort* __restrict__ Whb,        // [M][256] bf16
    float* __restrict__ alpha_s, float* __restrict__ alpha_d, int M)
{
  __shared__ ushort As[64 * 40];    // stride 40 bf16 (80B): 2-way (free) bank aliasing
  __shared__ ushort Bs[256 * 40];
  const int tid = threadIdx.x;
  const int wave = tid >> 6, lane = tid & 63;
  const int m0 = blockIdx.x * 64;
  const int row16 = lane & 15;
  const int kg = lane >> 4;        // k-group 0..3 -> k offset kg*8
  f32x4 acc[4][4] = {};

  const int a_r = tid >> 2;              // 0..63
  const int a_c = (tid & 3) * 8;         // bf16 col 0,8,16,24
  const int a_row = m0 + a_r;

  for (int k0 = 0; k0 < IN_F; k0 += 32) {
    // A staging: 8 f32 -> 8 bf16 per thread
    uint4 av = make_uint4(0, 0, 0, 0);
    if (a_row < M) {
      float4 f0 = *(const float4*)&A[(size_t)a_row * IN_F + k0 + a_c];
      float4 f1 = *(const float4*)&A[(size_t)a_row * IN_F + k0 + a_c + 4];
      av.x = (unsigned)f2bf(f0.x) | ((unsigned)f2bf(f0.y) << 16);
      av.y = (unsigned)f2bf(f0.z) | ((unsigned)f2bf(f0.w) << 16);
      av.z = (unsigned)f2bf(f1.x) | ((unsigned)f2bf(f1.y) << 16);
      av.w = (unsigned)f2bf(f1.z) | ((unsigned)f2bf(f1.w) << 16);
    }
    *(uint4*)&As[a_r * 40 + a_c] = av;
    const uint4* bp = (const uint4*)&Wt[(size_t)tid * IN_F + k0];
    uint4 b0 = bp[0], b1 = bp[1];
    *(uint4*)&Bs[tid * 40 + 0] = b0;
    *(uint4*)&Bs[tid * 40 + 8] = b1;
    uint4 b2 = bp[2], b3 = bp[3];
    *(uint4*)&Bs[tid * 40 + 16] = b2;
    *(uint4*)&Bs[tid * 40 + 24] = b3;
    __syncthreads();
    bf16x8 af[4], bfr[4];
#pragma unroll
    for (int mi = 0; mi < 4; ++mi)
      af[mi] = *(const bf16x8*)&As[(mi * 16 + row16) * 40 + kg * 8];
#pragma unroll
    for (int ni = 0; ni < 4; ++ni)
      bfr[ni] = *(const bf16x8*)&Bs[(wave * 64 + ni * 16 + row16) * 40 + kg * 8];
#pragma unroll
    for (int mi = 0; mi < 4; ++mi)
#pragma unroll
      for (int ni = 0; ni < 4; ++ni)
        acc[mi][ni] = __builtin_amdgcn_mfma_f32_16x16x32_bf16(af[mi], bfr[ni], acc[mi][ni], 0, 0, 0);
    __syncthreads();
  }

  // epilogue 1: alpha coefficients for this wave's two heads
  float cs[4], cd[4];
#pragma unroll
  for (int ni = 0; ni < 4; ++ni) {
    int hh = 2 * wave + (ni >> 1);
    int ff = (ni & 1) * 16 + row16;
    cs[ni] = a_src[hh * FOUT + ff];
    cd[ni] = a_dst[hh * FOUT + ff];
  }
  // C/D layout (m89-verified): col = lane&15 (row16), row = kg*4 + reg
#pragma unroll
  for (int mi = 0; mi < 4; ++mi) {
#pragma unroll
    for (int r = 0; r < 4; ++r) {
      int row = m0 + mi * 16 + kg * 4 + r;
      float ps0 = acc[mi][0][r] * cs[0] + acc[mi][1][r] * cs[1];
      float ps1 = acc[mi][2][r] * cs[2] + acc[mi][3][r] * cs[3];
      float pd0 = acc[mi][0][r] * cd[0] + acc[mi][1][r] * cd[1];
      float pd1 = acc[mi][2][r] * cd[2] + acc[mi][3][r] * cd[3];
#pragma unroll
      for (int msk = 1; msk <= 8; msk <<= 1) {
        ps0 += __shfl_xor(ps0, msk, 64);
        ps1 += __shfl_xor(ps1, msk, 64);
        pd0 += __shfl_xor(pd0, msk, 64);
        pd1 += __shfl_xor(pd1, msk, 64);
      }
      if (row16 == 0 && row < M) {
        *(float2*)&alpha_s[row * 8 + 2 * wave] = make_float2(ps0, ps1);
        *(float2*)&alpha_d[row * 8 + 2 * wave] = make_float2(pd0, pd1);
      }
      // epilogue 2: bf16 store of this row's 64 cols owned by the wave
      if (row < M) {
#pragma unroll
        for (int ni = 0; ni < 4; ++ni)
          Whb[(size_t)row * HF + wave * 64 + ni * 16 + row16] = f2bf(acc[mi][ni][r]);
      }
    }
  }
}

// ---------------- B[k,h] = sum_f We_w[k, h*32+f] * a_edge[h,f]  (64x8) ----------------
__global__ __launch_bounds__(256) void k_bmat(
    const float* __restrict__ We_w, const float* __restrict__ a_edge,
    float* __restrict__ Bmat)
{
  int i = blockIdx.x * 256 + threadIdx.x;
  if (i >= EDGE_F * HEADS) return;
  int k = i >> 3, h = i & 7;
  float s = 0.f;
#pragma unroll
  for (int f = 0; f < FOUT; ++f)
    s += We_w[k * HF + h * FOUT + f] * a_edge[h * FOUT + f];
  Bmat[i] = s;   // layout [k][h]
}

// ---------------- degree histogram ----------------
__global__ __launch_bounds__(256) void k_hist(const int* __restrict__ dst,
                                              int* __restrict__ deg)
{
  int e = blockIdx.x * 256 + threadIdx.x;
  if (e < N_EDGES) atomicAdd(&deg[dst[e]], 1);
}

// ---------------- exclusive scan: thread-serial chunks + one block scan ----------------
#define SCAN_ITEMS 49   // 1024*49 = 50176 >= N_NODES
__global__ __launch_bounds__(1024) void k_scan(const int* __restrict__ deg,
                                               int* __restrict__ offsets,
                                               int* __restrict__ cursor)
{
  __shared__ int sums[1024];
  int t = threadIdx.x;
  int base = t * SCAN_ITEMS;
  int s = 0;
  for (int i = 0; i < SCAN_ITEMS; ++i) {
    int idx = base + i;
    if (idx < N_NODES) s += deg[idx];
  }
  sums[t] = s;
  __syncthreads();
  int x = s;
  for (int off = 1; off < 1024; off <<= 1) {
    int y = (t >= off) ? sums[t - off] : 0;
    __syncthreads();
    x += y;
    sums[t] = x;
    __syncthreads();
  }
  int run = x - s;   // exclusive prefix of this thread's chunk
  for (int i = 0; i < SCAN_ITEMS; ++i) {
    int idx = base + i;
    if (idx < N_NODES) {
      offsets[idx] = run;
      cursor[idx] = run;
      run += deg[idx];
    }
  }
  if (t == 1023) offsets[N_NODES] = x;
}

// ---------------- edge logits IN EDGE ORDER (coalesced) + 8B CSR scatter ----------------
__global__ __launch_bounds__(256) void k_sedge(
    const float* __restrict__ ef, const int* __restrict__ src,
    const int* __restrict__ dst, const float* __restrict__ alpha_s,
    const float* __restrict__ alpha_d, const float* __restrict__ Bmat,
    int* __restrict__ cursor, float* __restrict__ s8,
    int2* __restrict__ srcE)
{
  __shared__ float Bs[EDGE_F * HEADS];
  for (int i = threadIdx.x; i < EDGE_F * HEADS; i += 256) Bs[i] = Bmat[i];
  __syncthreads();
  int e = blockIdx.x * 256 + threadIdx.x;
  if (e >= N_EDGES) return;
  int sn = src[e], dn = dst[e];
  float sc[8];
  {
    const float4* a1 = (const float4*)&alpha_s[sn * 8];
    const float4* a2 = (const float4*)&alpha_d[dn * 8];
    float4 p = a1[0], q = a1[1], r = a2[0], w = a2[1];
    sc[0] = p.x + r.x; sc[1] = p.y + r.y; sc[2] = p.z + r.z; sc[3] = p.w + r.w;
    sc[4] = q.x + w.x; sc[5] = q.y + w.y; sc[6] = q.z + w.z; sc[7] = q.w + w.w;
  }
  const float4* efr = (const float4*)&ef[(size_t)e * EDGE_F];
  for (int g = 0; g < EDGE_F / 4; ++g) {
    float4 v = efr[g];
    const float* b0 = &Bs[(g * 4) * 8];
#pragma unroll
    for (int hh = 0; hh < 8; ++hh)
      sc[hh] += v.x * b0[hh] + v.y * b0[8 + hh] + v.z * b0[16 + hh] + v.w * b0[24 + hh];
  }
#pragma unroll
  for (int hh = 0; hh < 8; ++hh)
    sc[hh] = sc[hh] > 0.f ? sc[hh] : 0.01f * sc[hh];
  // coalesced 32B write in edge order
  float4* o = (float4*)&s8[(size_t)e * 8];
  o[0] = make_float4(sc[0], sc[1], sc[2], sc[3]);
  o[1] = make_float4(sc[4], sc[5], sc[6], sc[7]);
  // only 8B scattered (L2-resident 6.4MB buffer)
  int p = atomicAdd(&cursor[dn], 1);
  srcE[p] = make_int2(sn, e);
}

// ---------------- per-node ONLINE softmax + bf16 pair-packed gather-sum + ELU ----------------
__global__ __launch_bounds__(256) void k_agg(
    const float* __restrict__ s8, const int2* __restrict__ srcE,
    const int* __restrict__ offsets, const uint* __restrict__ Whb_u,  // [N][128] uint = 2x bf16
    float* __restrict__ out)
{
  int n = blockIdx.x;
  int beg = offsets[n], end = offsets[n + 1];
  int t = threadIdx.x;
  const int h8 = t >> 5;    // head (softmax role)
  const int j = t & 31;     // edge slot (softmax role)
  const int p = t & 127;    // bf16-pair index (accumulate role): cols {2p,2p+1}
  const int g = t >> 7;     // edge parity group (accumulate role)
  const int hp = p >> 4;    // head of pair p
  __shared__ int s_idx[32];
  __shared__ int s_eid[32];
  __shared__ float s_w[8 * 33];   // [h8][j], pitch 33 -> 2-way (free) bank aliasing
  __shared__ float s_f[8], s_l[8];
  __shared__ float s_red[256];

  float m_run = -3.0e38f, l_run = 0.f;   // redundant per-lane, consistent within head group
  float acc0 = 0.f, acc1 = 0.f;

  for (int c0 = beg; c0 < end; c0 += 32) {
    int cnt = end - c0; cnt = cnt < 32 ? cnt : 32;
    if (t < cnt) { int2 r = srcE[c0 + t]; s_idx[t] = r.x; s_eid[t] = r.y; }
    __syncthreads();

    // ---- softmax role: (j, h8) ----
    float s = -3.0e38f;
    if (j < cnt) s = s8[(size_t)s_eid[j] * 8 + h8];
    float mc = s;
#pragma unroll
    for (int off = 16; off > 0; off >>= 1)
      mc = fmaxf(mc, __shfl_xor(mc, off, 32));
    float m_new = fmaxf(m_run, mc);
    float f = __expf(m_run - m_new);        // first chunk: exp(-3e38 - finite) = 0
    float w = (j < cnt) ? __expf(s - m_new) : 0.f;
    float ws = w;
#pragma unroll
    for (int off = 16; off > 0; off >>= 1)
      ws += __shfl_xor(ws, off, 32);
    l_run = l_run * f + ws;
    m_run = m_new;
    s_w[h8 * 33 + j] = w;
    if (j == 0) s_f[h8] = f;
    __syncthreads();

    // ---- accumulate role: (p, g) ----
    float fr = s_f[hp];
    acc0 *= fr; acc1 *= fr;
    for (int k = g; k < cnt; k += 2) {
      uint wv = Whb_u[(size_t)s_idx[k] * 128 + p];
      float wt = s_w[hp * 33 + k];
      acc0 = fmaf(wt, __uint_as_float(wv << 16), acc0);
      acc1 = fmaf(wt, __uint_as_float(wv & 0xFFFF0000u), acc1);
    }
    __syncthreads();   // protect s_idx/s_w before next chunk overwrites
  }

  if (j == 0) s_l[h8] = l_run;
  __syncthreads();
  float l = s_l[hp];
  float inv = (l > 0.f) ? 1.f / l : 0.f;
  acc0 *= inv; acc1 *= inv;

  // combine the two edge-parity groups, fused ELU, coalesced float2 store
  if (g) { s_red[p * 2] = acc0; s_red[p * 2 + 1] = acc1; }
  __syncthreads();
  if (!g) {
    acc0 += s_red[p * 2];
    acc1 += s_red[p * 2 + 1];
    float2 o;
    o.x = acc0 > 0.f ? acc0 : expm1f(acc0);
    o.y = acc1 > 0.f ? acc1 : expm1f(acc1);
    *(float2*)&out[(size_t)n * HF + p * 2] = o;
  }
}

extern "C" void kernel_launch(void* const* d_in, const int* in_sizes, int n_in,
                              void* d_out, int out_size, void* d_ws, size_t ws_size,
                              hipStream_t stream)
{
  const float* h    = (const float*)d_in[0];
  const float* ef   = (const float*)d_in[1];
  const int*   src  = (const int*)d_in[2];
  const int*   dst  = (const int*)d_in[3];
  const float* W_w  = (const float*)d_in[4];
  const float* We_w = (const float*)d_in[5];
  const float* a_s  = (const float*)d_in[6];
  const float* a_d  = (const float*)d_in[7];
  const float* a_e  = (const float*)d_in[8];
  float* out = (float*)d_out;

  char* ws = (char*)d_ws;
  size_t off = 0;
  auto take = [&](size_t bytes) {
    char* p = ws + off;
    off += (bytes + 255) & ~(size_t)255;
    return p;
  };
  ushort* Whb     = (ushort*)take((size_t)N_NODES * HF * 2);         // 25.6 MB bf16
  float* s8       = (float*)take((size_t)N_EDGES * HEADS * 4);       // 25.6 MB, EDGE order
  float* alpha_s  = (float*)take((size_t)N_NODES * HEADS * 4);
  float* alpha_d  = (float*)take((size_t)N_NODES * HEADS * 4);
  int2*  srcE     = (int2*)take((size_t)N_EDGES * 8);                // 6.4 MB
  int*   deg      = (int*)take((size_t)N_NODES * 4);
  int*   offs     = (int*)take((size_t)(N_NODES + 1) * 4);
  int*   cursor   = (int*)take((size_t)N_NODES * 4);
  float* Bmat     = (float*)take((size_t)EDGE_F * HEADS * 4);
  ushort* Wt      = (ushort*)take((size_t)HF * IN_F * 2);            // 128 KB

  (void)hipMemsetAsync(deg, 0, N_NODES * sizeof(int), stream);
  k_hist<<<(N_EDGES + 255) / 256, 256, 0, stream>>>(dst, deg);
  k_scan<<<1, 1024, 0, stream>>>(deg, offs, cursor);
  k_bmat<<<(EDGE_F * HEADS + 255) / 256, 256, 0, stream>>>(We_w, a_e, Bmat);
  k_cvtW<<<(HF * IN_F) / 256, 256, 0, stream>>>(W_w, Wt);
  k_gemm_fused<<<(N_NODES + 63) / 64, 256, 0, stream>>>(h, Wt, a_s, a_d, Whb,
                                                        alpha_s, alpha_d, N_NODES);
  k_sedge<<<(N_EDGES + 255) / 256, 256, 0, stream>>>(ef, src, dst, alpha_s, alpha_d,
                                                     Bmat, cursor, s8, srcE);
  k_agg<<<N_NODES, 256, 0, stream>>>(s8, srcE, offs, (const uint*)Whb, out);
}

// Round 6
// 448.561 us; speedup vs baseline: 1.2688x; 1.0340x over previous
//
#include <hip/hip_runtime.h>

#define N_NODES 50000
#define N_EDGES 800000
#define HEADS 8
#define FOUT 32
#define HF 256   // HEADS*FOUT
#define IN_F 256
#define EDGE_F 64

typedef __attribute__((ext_vector_type(8))) short bf16x8;
typedef __attribute__((ext_vector_type(4))) float f32x4;

__device__ inline ushort f2bf(float f) {  // round-to-nearest-even f32 -> bf16
  unsigned u = __float_as_uint(f);
  unsigned r = 0x7FFFu + ((u >> 16) & 1u);
  return (ushort)((u + r) >> 16);
}

// ---------------- convert + transpose W: Wt[n][k] = bf16(W[k][n]) ----------------
__global__ __launch_bounds__(256) void k_cvtW(const float* __restrict__ W,
                                              ushort* __restrict__ Wt)
{
  int i = blockIdx.x * 256 + threadIdx.x;   // output index, coalesced write
  int n = i >> 8, k = i & 255;
  Wt[i] = f2bf(W[k * HF + n]);
}

// ---------------- fused GEMM: Whb = bf16(h @ W), alpha_s/d from f32 accs ----------------
// Block: 64 rows x 256 cols, 4 waves; wave w owns cols [64w,64w+64) = heads {2w,2w+1}.
__global__ __launch_bounds__(256) void k_gemm_fused(
    const float* __restrict__ A,     // h [M][256] f32
    const ushort* __restrict__ Wt,   // [256 n][256 k] bf16, K-contig
    const float* __restrict__ a_src, const float* __restrict__ a_dst,
    ushort* __restrict__ Whb,        // [M][256] bf16
    float* __restrict__ alpha_s, float* __restrict__ alpha_d, int M)
{
  __shared__ ushort As[64 * 40];    // stride 40 bf16 (80B): 2-way (free) bank aliasing
  __shared__ ushort Bs[256 * 40];
  const int tid = threadIdx.x;
  const int wave = tid >> 6, lane = tid & 63;
  const int m0 = blockIdx.x * 64;
  const int row16 = lane & 15;
  const int kg = lane >> 4;        // k-group 0..3 -> k offset kg*8
  f32x4 acc[4][4] = {};

  const int a_r = tid >> 2;              // 0..63
  const int a_c = (tid & 3) * 8;         // bf16 col 0,8,16,24
  const int a_row = m0 + a_r;

  for (int k0 = 0; k0 < IN_F; k0 += 32) {
    // A staging: 8 f32 -> 8 bf16 per thread
    uint4 av = make_uint4(0, 0, 0, 0);
    if (a_row < M) {
      float4 f0 = *(const float4*)&A[(size_t)a_row * IN_F + k0 + a_c];
      float4 f1 = *(const float4*)&A[(size_t)a_row * IN_F + k0 + a_c + 4];
      av.x = (unsigned)f2bf(f0.x) | ((unsigned)f2bf(f0.y) << 16);
      av.y = (unsigned)f2bf(f0.z) | ((unsigned)f2bf(f0.w) << 16);
      av.z = (unsigned)f2bf(f1.x) | ((unsigned)f2bf(f1.y) << 16);
      av.w = (unsigned)f2bf(f1.z) | ((unsigned)f2bf(f1.w) << 16);
    }
    *(uint4*)&As[a_r * 40 + a_c] = av;
    const uint4* bp = (const uint4*)&Wt[(size_t)tid * IN_F + k0];
    uint4 b0 = bp[0], b1 = bp[1];
    *(uint4*)&Bs[tid * 40 + 0] = b0;
    *(uint4*)&Bs[tid * 40 + 8] = b1;
    uint4 b2 = bp[2], b3 = bp[3];
    *(uint4*)&Bs[tid * 40 + 16] = b2;
    *(uint4*)&Bs[tid * 40 + 24] = b3;
    __syncthreads();
    bf16x8 af[4], bfr[4];
#pragma unroll
    for (int mi = 0; mi < 4; ++mi)
      af[mi] = *(const bf16x8*)&As[(mi * 16 + row16) * 40 + kg * 8];
#pragma unroll
    for (int ni = 0; ni < 4; ++ni)
      bfr[ni] = *(const bf16x8*)&Bs[(wave * 64 + ni * 16 + row16) * 40 + kg * 8];
#pragma unroll
    for (int mi = 0; mi < 4; ++mi)
#pragma unroll
      for (int ni = 0; ni < 4; ++ni)
        acc[mi][ni] = __builtin_amdgcn_mfma_f32_16x16x32_bf16(af[mi], bfr[ni], acc[mi][ni], 0, 0, 0);
    __syncthreads();
  }

  // epilogue 1: alpha coefficients for this wave's two heads
  float cs[4], cd[4];
#pragma unroll
  for (int ni = 0; ni < 4; ++ni) {
    int hh = 2 * wave + (ni >> 1);
    int ff = (ni & 1) * 16 + row16;
    cs[ni] = a_src[hh * FOUT + ff];
    cd[ni] = a_dst[hh * FOUT + ff];
  }
  // C/D layout (m89-verified): col = lane&15 (row16), row = kg*4 + reg
#pragma unroll
  for (int mi = 0; mi < 4; ++mi) {
#pragma unroll
    for (int r = 0; r < 4; ++r) {
      int row = m0 + mi * 16 + kg * 4 + r;
      float ps0 = acc[mi][0][r] * cs[0] + acc[mi][1][r] * cs[1];
      float ps1 = acc[mi][2][r] * cs[2] + acc[mi][3][r] * cs[3];
      float pd0 = acc[mi][0][r] * cd[0] + acc[mi][1][r] * cd[1];
      float pd1 = acc[mi][2][r] * cd[2] + acc[mi][3][r] * cd[3];
#pragma unroll
      for (int msk = 1; msk <= 8; msk <<= 1) {
        ps0 += __shfl_xor(ps0, msk, 64);
        ps1 += __shfl_xor(ps1, msk, 64);
        pd0 += __shfl_xor(pd0, msk, 64);
        pd1 += __shfl_xor(pd1, msk, 64);
      }
      if (row16 == 0 && row < M) {
        *(float2*)&alpha_s[row * 8 + 2 * wave] = make_float2(ps0, ps1);
        *(float2*)&alpha_d[row * 8 + 2 * wave] = make_float2(pd0, pd1);
      }
      // epilogue 2: bf16 store of this row's 64 cols owned by the wave
      if (row < M) {
#pragma unroll
        for (int ni = 0; ni < 4; ++ni)
          Whb[(size_t)row * HF + wave * 64 + ni * 16 + row16] = f2bf(acc[mi][ni][r]);
      }
    }
  }
}

// ---------------- B[k,h] = sum_f We_w[k, h*32+f] * a_edge[h,f]  (64x8) ----------------
__global__ __launch_bounds__(256) void k_bmat(
    const float* __restrict__ We_w, const float* __restrict__ a_edge,
    float* __restrict__ Bmat)
{
  int i = blockIdx.x * 256 + threadIdx.x;
  if (i >= EDGE_F * HEADS) return;
  int k = i >> 3, h = i & 7;
  float s = 0.f;
#pragma unroll
  for (int f = 0; f < FOUT; ++f)
    s += We_w[k * HF + h * FOUT + f] * a_edge[h * FOUT + f];
  Bmat[i] = s;   // layout [k][h]
}

// ---------------- degree histogram ----------------
__global__ __launch_bounds__(256) void k_hist(const int* __restrict__ dst,
                                              int* __restrict__ deg)
{
  int e = blockIdx.x * 256 + threadIdx.x;
  if (e < N_EDGES) atomicAdd(&deg[dst[e]], 1);
}

// ---------------- exclusive scan: thread-serial chunks + one block scan ----------------
#define SCAN_ITEMS 49   // 1024*49 = 50176 >= N_NODES
__global__ __launch_bounds__(1024) void k_scan(const int* __restrict__ deg,
                                               int* __restrict__ offsets,
                                               int* __restrict__ cursor)
{
  __shared__ int sums[1024];
  int t = threadIdx.x;
  int base = t * SCAN_ITEMS;
  int s = 0;
  for (int i = 0; i < SCAN_ITEMS; ++i) {
    int idx = base + i;
    if (idx < N_NODES) s += deg[idx];
  }
  sums[t] = s;
  __syncthreads();
  int x = s;
  for (int off = 1; off < 1024; off <<= 1) {
    int y = (t >= off) ? sums[t - off] : 0;
    __syncthreads();
    x += y;
    sums[t] = x;
    __syncthreads();
  }
  int run = x - s;   // exclusive prefix of this thread's chunk
  for (int i = 0; i < SCAN_ITEMS; ++i) {
    int idx = base + i;
    if (idx < N_NODES) {
      offsets[idx] = run;
      cursor[idx] = run;
      run += deg[idx];
    }
  }
  if (t == 1023) offsets[N_NODES] = x;
}

// ---------------- CSR permutation only: 8B scatter per edge ----------------
__global__ __launch_bounds__(256) void k_perm(
    const int* __restrict__ src, const int* __restrict__ dst,
    int* __restrict__ cursor, int2* __restrict__ srcE)
{
  int e = blockIdx.x * 256 + threadIdx.x;
  if (e >= N_EDGES) return;
  int sn = src[e], dn = dst[e];
  int p = atomicAdd(&cursor[dn], 1);
  srcE[p] = make_int2(sn, e);
}

// ---------------- edge logits IN EDGE ORDER: pure coalesced stream ----------------
__global__ __launch_bounds__(256) void k_sedge(
    const float* __restrict__ ef, const int* __restrict__ src,
    const int* __restrict__ dst, const float* __restrict__ alpha_s,
    const float* __restrict__ alpha_d, const float* __restrict__ Bmat,
    float* __restrict__ s8)
{
  __shared__ float Bs[EDGE_F * HEADS];
  for (int i = threadIdx.x; i < EDGE_F * HEADS; i += 256) Bs[i] = Bmat[i];
  __syncthreads();
  int e = blockIdx.x * 256 + threadIdx.x;
  if (e >= N_EDGES) return;
  int sn = src[e], dn = dst[e];
  float sc[8];
  {
    const float4* a1 = (const float4*)&alpha_s[sn * 8];
    const float4* a2 = (const float4*)&alpha_d[dn * 8];
    float4 p = a1[0], q = a1[1], r = a2[0], w = a2[1];
    sc[0] = p.x + r.x; sc[1] = p.y + r.y; sc[2] = p.z + r.z; sc[3] = p.w + r.w;
    sc[4] = q.x + w.x; sc[5] = q.y + w.y; sc[6] = q.z + w.z; sc[7] = q.w + w.w;
  }
  const float4* efr = (const float4*)&ef[(size_t)e * EDGE_F];
#pragma unroll
  for (int g = 0; g < EDGE_F / 4; ++g) {
    float4 v = efr[g];
    const float* b0 = &Bs[(g * 4) * 8];
#pragma unroll
    for (int hh = 0; hh < 8; ++hh)
      sc[hh] += v.x * b0[hh] + v.y * b0[8 + hh] + v.z * b0[16 + hh] + v.w * b0[24 + hh];
  }
#pragma unroll
  for (int hh = 0; hh < 8; ++hh)
    sc[hh] = sc[hh] > 0.f ? sc[hh] : 0.01f * sc[hh];
  float4* o = (float4*)&s8[(size_t)e * 8];
  o[0] = make_float4(sc[0], sc[1], sc[2], sc[3]);
  o[1] = make_float4(sc[4], sc[5], sc[6], sc[7]);
}

// ---------------- WAVE-PER-NODE online softmax + bf16 gather-sum + ELU ----------------
// Lane roles: softmax = (head l&7, edge-slot l>>3); accumulate = lane owns uints
// {l, l+64} of the 128-uint output row -> heads h0=l>>4, h1=4+(l>>4). No barriers.
__global__ __launch_bounds__(256) void k_agg(
    const float* __restrict__ s8, const int2* __restrict__ srcE,
    const int* __restrict__ offsets, const uint* __restrict__ Whb_u,  // [N][128]
    float* __restrict__ out)
{
  const int n = blockIdx.x * 4 + (threadIdx.x >> 6);
  const int l = threadIdx.x & 63;
  const int beg = offsets[n], end = offsets[n + 1];
  const int h_sm = l & 7;    // softmax head
  const int es = l >> 3;     // softmax edge slot
  const int h0 = l >> 4;     // head of uint l
  const int h1 = 4 + h0;     // head of uint l+64

  float m_run = -3.0e38f, l_run = 0.f;
  float acc00 = 0.f, acc01 = 0.f, acc10 = 0.f, acc11 = 0.f;

  for (int c0 = beg; c0 < end; c0 += 8) {
    const int cnt = min(8, end - c0);
    int rx = 0, ry = 0;
    if (es < cnt) { int2 r = srcE[c0 + es]; rx = r.x; ry = r.y; }
    // chunk logit for (edge c0+es, head h_sm)
    float s = (es < cnt) ? s8[(size_t)ry * 8 + h_sm] : -3.0e38f;
    // chunk max over edge slots (lane bits 3,4,5)
    float mc = s;
    mc = fmaxf(mc, __shfl_xor(mc, 8, 64));
    mc = fmaxf(mc, __shfl_xor(mc, 16, 64));
    mc = fmaxf(mc, __shfl_xor(mc, 32, 64));
    float m_new = fmaxf(m_run, mc);
    float f = __expf(m_run - m_new);          // rescale factor (0 on first chunk)
    float w = (es < cnt) ? __expf(s - m_new) : 0.f;
    float ws = w;
    ws += __shfl_xor(ws, 8, 64);
    ws += __shfl_xor(ws, 16, 64);
    ws += __shfl_xor(ws, 32, 64);
    l_run = l_run * f + ws;
    m_run = m_new;
    // rescale accumulators (f for head h lives in lane h)
    float f0 = __shfl(f, h0, 64);
    float f1 = __shfl(f, h1, 64);
    acc00 *= f0; acc01 *= f0; acc10 *= f1; acc11 *= f1;
    // gather-accumulate
    for (int k = 0; k < cnt; ++k) {
      int idx = __shfl(rx, k << 3, 64);
      float w0 = __shfl(w, (k << 3) | h0, 64);
      float w1 = __shfl(w, (k << 3) | h1, 64);
      const uint* rowp = Whb_u + ((size_t)idx << 7);
      uint v0 = rowp[l];
      uint v1 = rowp[l + 64];
      acc00 = fmaf(w0, __uint_as_float(v0 << 16), acc00);
      acc01 = fmaf(w0, __uint_as_float(v0 & 0xFFFF0000u), acc01);
      acc10 = fmaf(w1, __uint_as_float(v1 << 16), acc10);
      acc11 = fmaf(w1, __uint_as_float(v1 & 0xFFFF0000u), acc11);
    }
  }

  float l0 = __shfl(l_run, h0, 64);
  float l1 = __shfl(l_run, h1, 64);
  float inv0 = (l0 > 0.f) ? 1.f / l0 : 0.f;
  float inv1 = (l1 > 0.f) ? 1.f / l1 : 0.f;
  acc00 *= inv0; acc01 *= inv0; acc10 *= inv1; acc11 *= inv1;

  float2 oA, oB;
  oA.x = acc00 > 0.f ? acc00 : expm1f(acc00);
  oA.y = acc01 > 0.f ? acc01 : expm1f(acc01);
  oB.x = acc10 > 0.f ? acc10 : expm1f(acc10);
  oB.y = acc11 > 0.f ? acc11 : expm1f(acc11);
  *(float2*)&out[(size_t)n * HF + 2 * l] = oA;
  *(float2*)&out[(size_t)n * HF + 128 + 2 * l] = oB;
}

extern "C" void kernel_launch(void* const* d_in, const int* in_sizes, int n_in,
                              void* d_out, int out_size, void* d_ws, size_t ws_size,
                              hipStream_t stream)
{
  const float* h    = (const float*)d_in[0];
  const float* ef   = (const float*)d_in[1];
  const int*   src  = (const int*)d_in[2];
  const int*   dst  = (const int*)d_in[3];
  const float* W_w  = (const float*)d_in[4];
  const float* We_w = (const float*)d_in[5];
  const float* a_s  = (const float*)d_in[6];
  const float* a_d  = (const float*)d_in[7];
  const float* a_e  = (const float*)d_in[8];
  float* out = (float*)d_out;

  char* ws = (char*)d_ws;
  size_t off = 0;
  auto take = [&](size_t bytes) {
    char* p = ws + off;
    off += (bytes + 255) & ~(size_t)255;
    return p;
  };
  ushort* Whb     = (ushort*)take((size_t)N_NODES * HF * 2);         // 25.6 MB bf16
  float* s8       = (float*)take((size_t)N_EDGES * HEADS * 4);       // 25.6 MB, EDGE order
  float* alpha_s  = (float*)take((size_t)N_NODES * HEADS * 4);
  float* alpha_d  = (float*)take((size_t)N_NODES * HEADS * 4);
  int2*  srcE     = (int2*)take((size_t)N_EDGES * 8);                // 6.4 MB
  int*   deg      = (int*)take((size_t)N_NODES * 4);
  int*   offs     = (int*)take((size_t)(N_NODES + 1) * 4);
  int*   cursor   = (int*)take((size_t)N_NODES * 4);
  float* Bmat     = (float*)take((size_t)EDGE_F * HEADS * 4);
  ushort* Wt      = (ushort*)take((size_t)HF * IN_F * 2);            // 128 KB

  (void)hipMemsetAsync(deg, 0, N_NODES * sizeof(int), stream);
  k_hist<<<(N_EDGES + 255) / 256, 256, 0, stream>>>(dst, deg);
  k_scan<<<1, 1024, 0, stream>>>(deg, offs, cursor);
  k_perm<<<(N_EDGES + 255) / 256, 256, 0, stream>>>(src, dst, cursor, srcE);
  k_bmat<<<(EDGE_F * HEADS + 255) / 256, 256, 0, stream>>>(We_w, a_e, Bmat);
  k_cvtW<<<(HF * IN_F) / 256, 256, 0, stream>>>(W_w, Wt);
  k_gemm_fused<<<(N_NODES + 63) / 64, 256, 0, stream>>>(h, Wt, a_s, a_d, Whb,
                                                        alpha_s, alpha_d, N_NODES);
  k_sedge<<<(N_EDGES + 255) / 256, 256, 0, stream>>>(ef, src, dst, alpha_s, alpha_d,
                                                     Bmat, s8);
  k_agg<<<N_NODES / 4, 256, 0, stream>>>(s8, srcE, offs, (const uint*)Whb, out);
}

// Round 7
// 339.140 us; speedup vs baseline: 1.6781x; 1.3226x over previous
//
#include <hip/hip_runtime.h>

#define N_NODES 50000
#define N_EDGES 800000
#define HEADS 8
#define FOUT 32
#define HF 256   // HEADS*FOUT
#define IN_F 256
#define EDGE_F 64
#define SCAN_BLOCKS 196   // ceil(50000/256)

typedef __attribute__((ext_vector_type(8))) short bf16x8;
typedef __attribute__((ext_vector_type(4))) float f32x4;

__device__ inline ushort f2bf(float f) {  // round-to-nearest-even f32 -> bf16
  unsigned u = __float_as_uint(f);
  unsigned r = 0x7FFFu + ((u >> 16) & 1u);
  return (ushort)((u + r) >> 16);
}

// ---------------- convert + transpose W: Wt[n][k] = bf16(W[k][n]) ----------------
__global__ __launch_bounds__(256) void k_cvtW(const float* __restrict__ W,
                                              ushort* __restrict__ Wt)
{
  int i = blockIdx.x * 256 + threadIdx.x;   // output index, coalesced write
  int n = i >> 8, k = i & 255;
  Wt[i] = f2bf(W[k * HF + n]);
}

// ---------------- fused GEMM: Whb = bf16(h @ W), alpha_s/d from f32 accs ----------------
// Block: 64 rows x 256 cols, 4 waves; wave w owns cols [64w,64w+64) = heads {2w,2w+1}.
__global__ __launch_bounds__(256) void k_gemm_fused(
    const float* __restrict__ A,     // h [M][256] f32
    const ushort* __restrict__ Wt,   // [256 n][256 k] bf16, K-contig
    const float* __restrict__ a_src, const float* __restrict__ a_dst,
    ushort* __restrict__ Whb,        // [M][256] bf16
    float* __restrict__ alpha_s, float* __restrict__ alpha_d, int M)
{
  __shared__ ushort As[64 * 40];    // stride 40 bf16 (80B): 2-way (free) bank aliasing
  __shared__ ushort Bs[256 * 40];
  const int tid = threadIdx.x;
  const int wave = tid >> 6, lane = tid & 63;
  const int m0 = blockIdx.x * 64;
  const int row16 = lane & 15;
  const int kg = lane >> 4;        // k-group 0..3 -> k offset kg*8
  f32x4 acc[4][4] = {};

  const int a_r = tid >> 2;              // 0..63
  const int a_c = (tid & 3) * 8;         // bf16 col 0,8,16,24
  const int a_row = m0 + a_r;

  for (int k0 = 0; k0 < IN_F; k0 += 32) {
    // A staging: 8 f32 -> 8 bf16 per thread
    uint4 av = make_uint4(0, 0, 0, 0);
    if (a_row < M) {
      float4 f0 = *(const float4*)&A[(size_t)a_row * IN_F + k0 + a_c];
      float4 f1 = *(const float4*)&A[(size_t)a_row * IN_F + k0 + a_c + 4];
      av.x = (unsigned)f2bf(f0.x) | ((unsigned)f2bf(f0.y) << 16);
      av.y = (unsigned)f2bf(f0.z) | ((unsigned)f2bf(f0.w) << 16);
      av.z = (unsigned)f2bf(f1.x) | ((unsigned)f2bf(f1.y) << 16);
      av.w = (unsigned)f2bf(f1.z) | ((unsigned)f2bf(f1.w) << 16);
    }
    *(uint4*)&As[a_r * 40 + a_c] = av;
    const uint4* bp = (const uint4*)&Wt[(size_t)tid * IN_F + k0];
    uint4 b0 = bp[0], b1 = bp[1];
    *(uint4*)&Bs[tid * 40 + 0] = b0;
    *(uint4*)&Bs[tid * 40 + 8] = b1;
    uint4 b2 = bp[2], b3 = bp[3];
    *(uint4*)&Bs[tid * 40 + 16] = b2;
    *(uint4*)&Bs[tid * 40 + 24] = b3;
    __syncthreads();
    bf16x8 af[4], bfr[4];
#pragma unroll
    for (int mi = 0; mi < 4; ++mi)
      af[mi] = *(const bf16x8*)&As[(mi * 16 + row16) * 40 + kg * 8];
#pragma unroll
    for (int ni = 0; ni < 4; ++ni)
      bfr[ni] = *(const bf16x8*)&Bs[(wave * 64 + ni * 16 + row16) * 40 + kg * 8];
#pragma unroll
    for (int mi = 0; mi < 4; ++mi)
#pragma unroll
      for (int ni = 0; ni < 4; ++ni)
        acc[mi][ni] = __builtin_amdgcn_mfma_f32_16x16x32_bf16(af[mi], bfr[ni], acc[mi][ni], 0, 0, 0);
    __syncthreads();
  }

  // epilogue 1: alpha coefficients for this wave's two heads
  float cs[4], cd[4];
#pragma unroll
  for (int ni = 0; ni < 4; ++ni) {
    int hh = 2 * wave + (ni >> 1);
    int ff = (ni & 1) * 16 + row16;
    cs[ni] = a_src[hh * FOUT + ff];
    cd[ni] = a_dst[hh * FOUT + ff];
  }
  // C/D layout (m89-verified): col = lane&15 (row16), row = kg*4 + reg
#pragma unroll
  for (int mi = 0; mi < 4; ++mi) {
#pragma unroll
    for (int r = 0; r < 4; ++r) {
      int row = m0 + mi * 16 + kg * 4 + r;
      float ps0 = acc[mi][0][r] * cs[0] + acc[mi][1][r] * cs[1];
      float ps1 = acc[mi][2][r] * cs[2] + acc[mi][3][r] * cs[3];
      float pd0 = acc[mi][0][r] * cd[0] + acc[mi][1][r] * cd[1];
      float pd1 = acc[mi][2][r] * cd[2] + acc[mi][3][r] * cd[3];
#pragma unroll
      for (int msk = 1; msk <= 8; msk <<= 1) {
        ps0 += __shfl_xor(ps0, msk, 64);
        ps1 += __shfl_xor(ps1, msk, 64);
        pd0 += __shfl_xor(pd0, msk, 64);
        pd1 += __shfl_xor(pd1, msk, 64);
      }
      if (row16 == 0 && row < M) {
        *(float2*)&alpha_s[row * 8 + 2 * wave] = make_float2(ps0, ps1);
        *(float2*)&alpha_d[row * 8 + 2 * wave] = make_float2(pd0, pd1);
      }
      // epilogue 2: bf16 store of this row's 64 cols owned by the wave
      if (row < M) {
#pragma unroll
        for (int ni = 0; ni < 4; ++ni)
          Whb[(size_t)row * HF + wave * 64 + ni * 16 + row16] = f2bf(acc[mi][ni][r]);
      }
    }
  }
}

// ---------------- B[k,h] = sum_f We_w[k, h*32+f] * a_edge[h,f]  (64x8) ----------------
__global__ __launch_bounds__(256) void k_bmat(
    const float* __restrict__ We_w, const float* __restrict__ a_edge,
    float* __restrict__ Bmat)
{
  int i = blockIdx.x * 256 + threadIdx.x;
  if (i >= EDGE_F * HEADS) return;
  int k = i >> 3, h = i & 7;
  float s = 0.f;
#pragma unroll
  for (int f = 0; f < FOUT; ++f)
    s += We_w[k * HF + h * FOUT + f] * a_edge[h * FOUT + f];
  Bmat[i] = s;   // layout [k][h]
}

// ---------------- degree histogram ----------------
__global__ __launch_bounds__(256) void k_hist(const int* __restrict__ dst,
                                              int* __restrict__ deg)
{
  int e = blockIdx.x * 256 + threadIdx.x;
  if (e < N_EDGES) atomicAdd(&deg[dst[e]], 1);
}

// ---------------- hierarchical scan, phase A: per-block sums (coalesced) ----------------
__global__ __launch_bounds__(256) void k_scanA(const int* __restrict__ deg,
                                               int* __restrict__ blockSums)
{
  __shared__ int ws[4];
  int idx = blockIdx.x * 256 + threadIdx.x;
  int v = (idx < N_NODES) ? deg[idx] : 0;
  int s = v;
#pragma unroll
  for (int off = 32; off > 0; off >>= 1)
    s += __shfl_xor(s, off, 64);
  if ((threadIdx.x & 63) == 0) ws[threadIdx.x >> 6] = s;
  __syncthreads();
  if (threadIdx.x == 0)
    blockSums[blockIdx.x] = ws[0] + ws[1] + ws[2] + ws[3];
}

// ---------------- phase B: scan the block sums (1 small block) ----------------
__global__ __launch_bounds__(256) void k_scanB(const int* __restrict__ blockSums,
                                               int* __restrict__ blockPre,
                                               int* __restrict__ offsets)
{
  __shared__ int tmp[256];
  int t = threadIdx.x;
  int v = (t < SCAN_BLOCKS) ? blockSums[t] : 0;
  tmp[t] = v;
  __syncthreads();
  int x = v;
  for (int off = 1; off < 256; off <<= 1) {
    int y = (t >= off) ? tmp[t - off] : 0;
    __syncthreads();
    x += y;
    tmp[t] = x;
    __syncthreads();
  }
  if (t < SCAN_BLOCKS) blockPre[t] = x - v;   // exclusive
  if (t == 255) offsets[N_NODES] = x;         // grand total
}

// ---------------- phase C: block-local scan + base, coalesced writes ----------------
__global__ __launch_bounds__(256) void k_scanC(const int* __restrict__ deg,
                                               const int* __restrict__ blockPre,
                                               int* __restrict__ offsets,
                                               int* __restrict__ cursor)
{
  __shared__ int tmp[256];
  int t = threadIdx.x;
  int idx = blockIdx.x * 256 + t;
  int v = (idx < N_NODES) ? deg[idx] : 0;
  tmp[t] = v;
  __syncthreads();
  int x = v;
  for (int off = 1; off < 256; off <<= 1) {
    int y = (t >= off) ? tmp[t - off] : 0;
    __syncthreads();
    x += y;
    tmp[t] = x;
    __syncthreads();
  }
  if (idx < N_NODES) {
    int pre = blockPre[blockIdx.x] + x - v;
    offsets[idx] = pre;
    cursor[idx] = pre;
  }
}

// ---------------- CSR permutation only: 8B scatter per edge ----------------
__global__ __launch_bounds__(256) void k_perm(
    const int* __restrict__ src, const int* __restrict__ dst,
    int* __restrict__ cursor, int2* __restrict__ srcE)
{
  int e = blockIdx.x * 256 + threadIdx.x;
  if (e >= N_EDGES) return;
  int sn = src[e], dn = dst[e];
  int p = atomicAdd(&cursor[dn], 1);
  srcE[p] = make_int2(sn, e);
}

// ---------------- edge logits IN EDGE ORDER: pure coalesced stream ----------------
__global__ __launch_bounds__(256) void k_sedge(
    const float* __restrict__ ef, const int* __restrict__ src,
    const int* __restrict__ dst, const float* __restrict__ alpha_s,
    const float* __restrict__ alpha_d, const float* __restrict__ Bmat,
    float* __restrict__ s8)
{
  __shared__ float Bs[EDGE_F * HEADS];
  for (int i = threadIdx.x; i < EDGE_F * HEADS; i += 256) Bs[i] = Bmat[i];
  __syncthreads();
  int e = blockIdx.x * 256 + threadIdx.x;
  if (e >= N_EDGES) return;
  int sn = src[e], dn = dst[e];
  float sc[8];
  {
    const float4* a1 = (const float4*)&alpha_s[sn * 8];
    const float4* a2 = (const float4*)&alpha_d[dn * 8];
    float4 p = a1[0], q = a1[1], r = a2[0], w = a2[1];
    sc[0] = p.x + r.x; sc[1] = p.y + r.y; sc[2] = p.z + r.z; sc[3] = p.w + r.w;
    sc[4] = q.x + w.x; sc[5] = q.y + w.y; sc[6] = q.z + w.z; sc[7] = q.w + w.w;
  }
  const float4* efr = (const float4*)&ef[(size_t)e * EDGE_F];
#pragma unroll
  for (int g = 0; g < EDGE_F / 4; ++g) {
    float4 v = efr[g];
    const float* b0 = &Bs[(g * 4) * 8];
#pragma unroll
    for (int hh = 0; hh < 8; ++hh)
      sc[hh] += v.x * b0[hh] + v.y * b0[8 + hh] + v.z * b0[16 + hh] + v.w * b0[24 + hh];
  }
#pragma unroll
  for (int hh = 0; hh < 8; ++hh)
    sc[hh] = sc[hh] > 0.f ? sc[hh] : 0.01f * sc[hh];
  float4* o = (float4*)&s8[(size_t)e * 8];
  o[0] = make_float4(sc[0], sc[1], sc[2], sc[3]);
  o[1] = make_float4(sc[4], sc[5], sc[6], sc[7]);
}

// ---------------- WAVE-PER-NODE online softmax + bf16 gather-sum + ELU ----------------
// Lane roles: softmax = (head l&7, edge-slot l>>3); accumulate = lane owns uints
// {l, l+64} of the 128-uint output row -> heads h0=l>>4, h1=4+(l>>4). No barriers.
__global__ __launch_bounds__(256) void k_agg(
    const float* __restrict__ s8, const int2* __restrict__ srcE,
    const int* __restrict__ offsets, const uint* __restrict__ Whb_u,  // [N][128]
    float* __restrict__ out)
{
  const int n = blockIdx.x * 4 + (threadIdx.x >> 6);
  const int l = threadIdx.x & 63;
  const int beg = offsets[n], end = offsets[n + 1];
  const int h_sm = l & 7;    // softmax head
  const int es = l >> 3;     // softmax edge slot
  const int h0 = l >> 4;     // head of uint l
  const int h1 = 4 + h0;     // head of uint l+64

  float m_run = -3.0e38f, l_run = 0.f;
  float acc00 = 0.f, acc01 = 0.f, acc10 = 0.f, acc11 = 0.f;

  for (int c0 = beg; c0 < end; c0 += 8) {
    const int cnt = min(8, end - c0);
    int rx = 0, ry = 0;
    if (es < cnt) { int2 r = srcE[c0 + es]; rx = r.x; ry = r.y; }
    // chunk logit for (edge c0+es, head h_sm)
    float s = (es < cnt) ? s8[(size_t)ry * 8 + h_sm] : -3.0e38f;
    // chunk max over edge slots (lane bits 3,4,5)
    float mc = s;
    mc = fmaxf(mc, __shfl_xor(mc, 8, 64));
    mc = fmaxf(mc, __shfl_xor(mc, 16, 64));
    mc = fmaxf(mc, __shfl_xor(mc, 32, 64));
    float m_new = fmaxf(m_run, mc);
    float f = __expf(m_run - m_new);          // rescale factor (0 on first chunk)
    float w = (es < cnt) ? __expf(s - m_new) : 0.f;
    float ws = w;
    ws += __shfl_xor(ws, 8, 64);
    ws += __shfl_xor(ws, 16, 64);
    ws += __shfl_xor(ws, 32, 64);
    l_run = l_run * f + ws;
    m_run = m_new;
    // rescale accumulators (f for head h lives in lane h)
    float f0 = __shfl(f, h0, 64);
    float f1 = __shfl(f, h1, 64);
    acc00 *= f0; acc01 *= f0; acc10 *= f1; acc11 *= f1;
    // gather-accumulate
    for (int k = 0; k < cnt; ++k) {
      int idx = __shfl(rx, k << 3, 64);
      float w0 = __shfl(w, (k << 3) | h0, 64);
      float w1 = __shfl(w, (k << 3) | h1, 64);
      const uint* rowp = Whb_u + ((size_t)idx << 7);
      uint v0 = rowp[l];
      uint v1 = rowp[l + 64];
      acc00 = fmaf(w0, __uint_as_float(v0 << 16), acc00);
      acc01 = fmaf(w0, __uint_as_float(v0 & 0xFFFF0000u), acc01);
      acc10 = fmaf(w1, __uint_as_float(v1 << 16), acc10);
      acc11 = fmaf(w1, __uint_as_float(v1 & 0xFFFF0000u), acc11);
    }
  }

  float l0 = __shfl(l_run, h0, 64);
  float l1 = __shfl(l_run, h1, 64);
  float inv0 = (l0 > 0.f) ? 1.f / l0 : 0.f;
  float inv1 = (l1 > 0.f) ? 1.f / l1 : 0.f;
  acc00 *= inv0; acc01 *= inv0; acc10 *= inv1; acc11 *= inv1;

  float2 oA, oB;
  oA.x = acc00 > 0.f ? acc00 : expm1f(acc00);
  oA.y = acc01 > 0.f ? acc01 : expm1f(acc01);
  oB.x = acc10 > 0.f ? acc10 : expm1f(acc10);
  oB.y = acc11 > 0.f ? acc11 : expm1f(acc11);
  *(float2*)&out[(size_t)n * HF + 2 * l] = oA;
  *(float2*)&out[(size_t)n * HF + 128 + 2 * l] = oB;
}

extern "C" void kernel_launch(void* const* d_in, const int* in_sizes, int n_in,
                              void* d_out, int out_size, void* d_ws, size_t ws_size,
                              hipStream_t stream)
{
  const float* h    = (const float*)d_in[0];
  const float* ef   = (const float*)d_in[1];
  const int*   src  = (const int*)d_in[2];
  const int*   dst  = (const int*)d_in[3];
  const float* W_w  = (const float*)d_in[4];
  const float* We_w = (const float*)d_in[5];
  const float* a_s  = (const float*)d_in[6];
  const float* a_d  = (const float*)d_in[7];
  const float* a_e  = (const float*)d_in[8];
  float* out = (float*)d_out;

  char* ws = (char*)d_ws;
  size_t off = 0;
  auto take = [&](size_t bytes) {
    char* p = ws + off;
    off += (bytes + 255) & ~(size_t)255;
    return p;
  };
  ushort* Whb     = (ushort*)take((size_t)N_NODES * HF * 2);         // 25.6 MB bf16
  float* s8       = (float*)take((size_t)N_EDGES * HEADS * 4);       // 25.6 MB, EDGE order
  float* alpha_s  = (float*)take((size_t)N_NODES * HEADS * 4);
  float* alpha_d  = (float*)take((size_t)N_NODES * HEADS * 4);
  int2*  srcE     = (int2*)take((size_t)N_EDGES * 8);                // 6.4 MB
  int*   deg      = (int*)take((size_t)N_NODES * 4);
  int*   offs     = (int*)take((size_t)(N_NODES + 1) * 4);
  int*   cursor   = (int*)take((size_t)N_NODES * 4);
  float* Bmat     = (float*)take((size_t)EDGE_F * HEADS * 4);
  ushort* Wt      = (ushort*)take((size_t)HF * IN_F * 2);            // 128 KB
  int*   blockSums= (int*)take((size_t)SCAN_BLOCKS * 4);
  int*   blockPre = (int*)take((size_t)SCAN_BLOCKS * 4);

  (void)hipMemsetAsync(deg, 0, N_NODES * sizeof(int), stream);
  k_hist<<<(N_EDGES + 255) / 256, 256, 0, stream>>>(dst, deg);
  k_scanA<<<SCAN_BLOCKS, 256, 0, stream>>>(deg, blockSums);
  k_scanB<<<1, 256, 0, stream>>>(blockSums, blockPre, offs);
  k_scanC<<<SCAN_BLOCKS, 256, 0, stream>>>(deg, blockPre, offs, cursor);
  k_perm<<<(N_EDGES + 255) / 256, 256, 0, stream>>>(src, dst, cursor, srcE);
  k_bmat<<<(EDGE_F * HEADS + 255) / 256, 256, 0, stream>>>(We_w, a_e, Bmat);
  k_cvtW<<<(HF * IN_F) / 256, 256, 0, stream>>>(W_w, Wt);
  k_gemm_fused<<<(N_NODES + 63) / 64, 256, 0, stream>>>(h, Wt, a_s, a_d, Whb,
                                                        alpha_s, alpha_d, N_NODES);
  k_sedge<<<(N_EDGES + 255) / 256, 256, 0, stream>>>(ef, src, dst, alpha_s, alpha_d,
                                                     Bmat, s8);
  k_agg<<<N_NODES / 4, 256, 0, stream>>>(s8, srcE, offs, (const uint*)Whb, out);
}

// Round 8
// 288.836 us; speedup vs baseline: 1.9704x; 1.1742x over previous
//
#include <hip/hip_runtime.h>

#define N_NODES 50000
#define N_EDGES 800000
#define HEADS 8
#define FOUT 32
#define HF 256   // HEADS*FOUT
#define IN_F 256
#define EDGE_F 64
#define SCAN_BLOCKS 196       // ceil(50000/256)
#define HIST_BLOCKS 3125      // 800000/256 exact
#define CVTW_BLOCKS 256       // 65536/256

typedef __attribute__((ext_vector_type(8))) short bf16x8;
typedef __attribute__((ext_vector_type(4))) float f32x4;

__device__ inline ushort f2bf(float f) {  // round-to-nearest-even f32 -> bf16
  unsigned u = __float_as_uint(f);
  unsigned r = 0x7FFFu + ((u >> 16) & 1u);
  return (ushort)((u + r) >> 16);
}

// ---------------- fused independent prep: hist | cvtW | bmat (block-range split) ----------------
__global__ __launch_bounds__(256) void k_misc(
    const int* __restrict__ dst, int* __restrict__ deg,
    const float* __restrict__ W, ushort* __restrict__ Wt,
    const float* __restrict__ We_w, const float* __restrict__ a_edge,
    float* __restrict__ Bmat)
{
  int b = blockIdx.x;
  if (b < HIST_BLOCKS) {
    int e = b * 256 + threadIdx.x;
    atomicAdd(&deg[dst[e]], 1);
  } else if (b < HIST_BLOCKS + CVTW_BLOCKS) {
    int i = (b - HIST_BLOCKS) * 256 + threadIdx.x;  // Wt[n][k] = bf16(W[k][n])
    int n = i >> 8, k = i & 255;
    Wt[i] = f2bf(W[k * HF + n]);
  } else {
    int i = (b - HIST_BLOCKS - CVTW_BLOCKS) * 256 + threadIdx.x;
    if (i < EDGE_F * HEADS) {
      int k = i >> 3, h = i & 7;
      float s = 0.f;
#pragma unroll
      for (int f = 0; f < FOUT; ++f)
        s += We_w[k * HF + h * FOUT + f] * a_edge[h * FOUT + f];
      Bmat[i] = s;   // layout [k][h]
    }
  }
}

// ---------------- fused GEMM: Whb = bf16(h @ W), alpha_s/d from f32 accs ----------------
__global__ __launch_bounds__(256) void k_gemm_fused(
    const float* __restrict__ A,     // h [M][256] f32
    const ushort* __restrict__ Wt,   // [256 n][256 k] bf16, K-contig
    const float* __restrict__ a_src, const float* __restrict__ a_dst,
    ushort* __restrict__ Whb,        // [M][256] bf16
    float* __restrict__ alpha_s, float* __restrict__ alpha_d, int M)
{
  __shared__ ushort As[64 * 40];    // stride 40 bf16 (80B): 2-way (free) bank aliasing
  __shared__ ushort Bs[256 * 40];
  const int tid = threadIdx.x;
  const int wave = tid >> 6, lane = tid & 63;
  const int m0 = blockIdx.x * 64;
  const int row16 = lane & 15;
  const int kg = lane >> 4;        // k-group 0..3 -> k offset kg*8
  f32x4 acc[4][4] = {};

  const int a_r = tid >> 2;              // 0..63
  const int a_c = (tid & 3) * 8;         // bf16 col 0,8,16,24
  const int a_row = m0 + a_r;

  for (int k0 = 0; k0 < IN_F; k0 += 32) {
    uint4 av = make_uint4(0, 0, 0, 0);
    if (a_row < M) {
      float4 f0 = *(const float4*)&A[(size_t)a_row * IN_F + k0 + a_c];
      float4 f1 = *(const float4*)&A[(size_t)a_row * IN_F + k0 + a_c + 4];
      av.x = (unsigned)f2bf(f0.x) | ((unsigned)f2bf(f0.y) << 16);
      av.y = (unsigned)f2bf(f0.z) | ((unsigned)f2bf(f0.w) << 16);
      av.z = (unsigned)f2bf(f1.x) | ((unsigned)f2bf(f1.y) << 16);
      av.w = (unsigned)f2bf(f1.z) | ((unsigned)f2bf(f1.w) << 16);
    }
    *(uint4*)&As[a_r * 40 + a_c] = av;
    const uint4* bp = (const uint4*)&Wt[(size_t)tid * IN_F + k0];
    uint4 b0 = bp[0], b1 = bp[1];
    *(uint4*)&Bs[tid * 40 + 0] = b0;
    *(uint4*)&Bs[tid * 40 + 8] = b1;
    uint4 b2 = bp[2], b3 = bp[3];
    *(uint4*)&Bs[tid * 40 + 16] = b2;
    *(uint4*)&Bs[tid * 40 + 24] = b3;
    __syncthreads();
    bf16x8 af[4], bfr[4];
#pragma unroll
    for (int mi = 0; mi < 4; ++mi)
      af[mi] = *(const bf16x8*)&As[(mi * 16 + row16) * 40 + kg * 8];
#pragma unroll
    for (int ni = 0; ni < 4; ++ni)
      bfr[ni] = *(const bf16x8*)&Bs[(wave * 64 + ni * 16 + row16) * 40 + kg * 8];
#pragma unroll
    for (int mi = 0; mi < 4; ++mi)
#pragma unroll
      for (int ni = 0; ni < 4; ++ni)
        acc[mi][ni] = __builtin_amdgcn_mfma_f32_16x16x32_bf16(af[mi], bfr[ni], acc[mi][ni], 0, 0, 0);
    __syncthreads();
  }

  float cs[4], cd[4];
#pragma unroll
  for (int ni = 0; ni < 4; ++ni) {
    int hh = 2 * wave + (ni >> 1);
    int ff = (ni & 1) * 16 + row16;
    cs[ni] = a_src[hh * FOUT + ff];
    cd[ni] = a_dst[hh * FOUT + ff];
  }
  // C/D layout (m89-verified): col = lane&15 (row16), row = kg*4 + reg
#pragma unroll
  for (int mi = 0; mi < 4; ++mi) {
#pragma unroll
    for (int r = 0; r < 4; ++r) {
      int row = m0 + mi * 16 + kg * 4 + r;
      float ps0 = acc[mi][0][r] * cs[0] + acc[mi][1][r] * cs[1];
      float ps1 = acc[mi][2][r] * cs[2] + acc[mi][3][r] * cs[3];
      float pd0 = acc[mi][0][r] * cd[0] + acc[mi][1][r] * cd[1];
      float pd1 = acc[mi][2][r] * cd[2] + acc[mi][3][r] * cd[3];
#pragma unroll
      for (int msk = 1; msk <= 8; msk <<= 1) {
        ps0 += __shfl_xor(ps0, msk, 64);
        ps1 += __shfl_xor(ps1, msk, 64);
        pd0 += __shfl_xor(pd0, msk, 64);
        pd1 += __shfl_xor(pd1, msk, 64);
      }
      if (row16 == 0 && row < M) {
        *(float2*)&alpha_s[row * 8 + 2 * wave] = make_float2(ps0, ps1);
        *(float2*)&alpha_d[row * 8 + 2 * wave] = make_float2(pd0, pd1);
      }
      if (row < M) {
#pragma unroll
        for (int ni = 0; ni < 4; ++ni)
          Whb[(size_t)row * HF + wave * 64 + ni * 16 + row16] = f2bf(acc[mi][ni][r]);
      }
    }
  }
}

// ---------------- hierarchical scan, phase A: per-block sums (coalesced) ----------------
__global__ __launch_bounds__(256) void k_scanA(const int* __restrict__ deg,
                                               int* __restrict__ blockSums)
{
  __shared__ int ws[4];
  int idx = blockIdx.x * 256 + threadIdx.x;
  int v = (idx < N_NODES) ? deg[idx] : 0;
  int s = v;
#pragma unroll
  for (int off = 32; off > 0; off >>= 1)
    s += __shfl_xor(s, off, 64);
  if ((threadIdx.x & 63) == 0) ws[threadIdx.x >> 6] = s;
  __syncthreads();
  if (threadIdx.x == 0)
    blockSums[blockIdx.x] = ws[0] + ws[1] + ws[2] + ws[3];
}

// ---------------- phase C (absorbs B): every block re-scans blockSums, then local scan ----------------
__global__ __launch_bounds__(256) void k_scanC(const int* __restrict__ deg,
                                               const int* __restrict__ blockSums,
                                               int* __restrict__ offsets,
                                               int* __restrict__ cursor)
{
  __shared__ int tmp[256];
  __shared__ int s_base;
  int t = threadIdx.x;
  int v = (t < SCAN_BLOCKS) ? blockSums[t] : 0;
  tmp[t] = v;
  __syncthreads();
  int x = v;
  for (int off = 1; off < 256; off <<= 1) {
    int y = (t >= off) ? tmp[t - off] : 0;
    __syncthreads();
    x += y;
    tmp[t] = x;
    __syncthreads();
  }
  if (t == (int)blockIdx.x) s_base = x - v;                 // exclusive prefix of this block
  if (blockIdx.x == 0 && t == 255) offsets[N_NODES] = x;    // grand total
  __syncthreads();
  int base = s_base;
  int idx = blockIdx.x * 256 + t;
  int d = (idx < N_NODES) ? deg[idx] : 0;
  tmp[t] = d;
  __syncthreads();
  int x2 = d;
  for (int off = 1; off < 256; off <<= 1) {
    int y = (t >= off) ? tmp[t - off] : 0;
    __syncthreads();
    x2 += y;
    tmp[t] = x2;
    __syncthreads();
  }
  if (idx < N_NODES) {
    int pre = base + x2 - d;
    offsets[idx] = pre;
    cursor[idx] = pre;
  }
}

// ---------------- edge logits (coalesced stream) + fused 8B CSR scatter ----------------
__global__ __launch_bounds__(256) void k_sedge(
    const float* __restrict__ ef, const int* __restrict__ src,
    const int* __restrict__ dst, const float* __restrict__ alpha_s,
    const float* __restrict__ alpha_d, const float* __restrict__ Bmat,
    int* __restrict__ cursor, float* __restrict__ s8,
    int2* __restrict__ srcE)
{
  __shared__ float Bs[EDGE_F * HEADS];
  for (int i = threadIdx.x; i < EDGE_F * HEADS; i += 256) Bs[i] = Bmat[i];
  __syncthreads();
  int e = blockIdx.x * 256 + threadIdx.x;
  if (e >= N_EDGES) return;
  int sn = src[e], dn = dst[e];
  // 8B scatter into L2-resident 6.4MB buffer (no RFO problem; atomic is cheap)
  int p = atomicAdd(&cursor[dn], 1);
  srcE[p] = make_int2(sn, e);
  float sc[8];
  {
    const float4* a1 = (const float4*)&alpha_s[sn * 8];
    const float4* a2 = (const float4*)&alpha_d[dn * 8];
    float4 pp = a1[0], q = a1[1], r = a2[0], w = a2[1];
    sc[0] = pp.x + r.x; sc[1] = pp.y + r.y; sc[2] = pp.z + r.z; sc[3] = pp.w + r.w;
    sc[4] = q.x + w.x; sc[5] = q.y + w.y; sc[6] = q.z + w.z; sc[7] = q.w + w.w;
  }
  const float4* efr = (const float4*)&ef[(size_t)e * EDGE_F];
#pragma unroll
  for (int g = 0; g < EDGE_F / 4; ++g) {
    float4 v = efr[g];
    const float* b0 = &Bs[(g * 4) * 8];
#pragma unroll
    for (int hh = 0; hh < 8; ++hh)
      sc[hh] += v.x * b0[hh] + v.y * b0[8 + hh] + v.z * b0[16 + hh] + v.w * b0[24 + hh];
  }
#pragma unroll
  for (int hh = 0; hh < 8; ++hh)
    sc[hh] = sc[hh] > 0.f ? sc[hh] : 0.01f * sc[hh];
  float4* o = (float4*)&s8[(size_t)e * 8];
  o[0] = make_float4(sc[0], sc[1], sc[2], sc[3]);
  o[1] = make_float4(sc[4], sc[5], sc[6], sc[7]);
}

// ---------------- WAVE-PER-NODE online softmax + prefetched, unrolled bf16 gather ----------------
__global__ __launch_bounds__(256) void k_agg(
    const float* __restrict__ s8, const int2* __restrict__ srcE,
    const int* __restrict__ offsets, const uint* __restrict__ Whb_u,  // [N][128]
    float* __restrict__ out)
{
  const int n = blockIdx.x * 4 + (threadIdx.x >> 6);
  const int l = threadIdx.x & 63;
  const int beg = offsets[n], end = offsets[n + 1];
  const int h_sm = l & 7;    // softmax head
  const int es = l >> 3;     // softmax edge slot
  const int h0 = l >> 4;     // head of uint l
  const int h1 = 4 + h0;     // head of uint l+64

  float m_run = -3.0e38f, l_run = 0.f;
  float acc00 = 0.f, acc01 = 0.f, acc10 = 0.f, acc11 = 0.f;

  // prefetch chunk 0
  int rx = 0;
  float s_cur = -3.0e38f;
  if (beg + es < end) {
    int2 r = srcE[beg + es];
    rx = r.x;
    s_cur = s8[(size_t)r.y * 8 + h_sm];
  }

  for (int c0 = beg; c0 < end; c0 += 8) {
    const int cnt = min(8, end - c0);
    // issue next chunk's loads early (hidden under this chunk's compute+gather)
    int rx_n = 0;
    float s_n = -3.0e38f;
    if (c0 + 8 + es < end) {
      int2 r = srcE[c0 + 8 + es];
      rx_n = r.x;
      s_n = s8[(size_t)r.y * 8 + h_sm];
    }
    float s = s_cur;
    float mc = s;
    mc = fmaxf(mc, __shfl_xor(mc, 8, 64));
    mc = fmaxf(mc, __shfl_xor(mc, 16, 64));
    mc = fmaxf(mc, __shfl_xor(mc, 32, 64));
    float m_new = fmaxf(m_run, mc);
    float f = __expf(m_run - m_new);          // 0 on first chunk
    float w = __expf(s - m_new);              // 0 for invalid slots (s=-3e38)
    float ws = w;
    ws += __shfl_xor(ws, 8, 64);
    ws += __shfl_xor(ws, 16, 64);
    ws += __shfl_xor(ws, 32, 64);
    l_run = l_run * f + ws;
    m_run = m_new;
    float f0 = __shfl(f, h0, 64);
    float f1 = __shfl(f, h1, 64);
    acc00 *= f0; acc01 *= f0; acc10 *= f1; acc11 *= f1;
    if (cnt == 8) {
#pragma unroll
      for (int k = 0; k < 8; ++k) {
        int idx = __shfl(rx, k << 3, 64);
        float w0 = __shfl(w, (k << 3) | h0, 64);
        float w1 = __shfl(w, (k << 3) | h1, 64);
        const uint* rowp = Whb_u + ((size_t)idx << 7);
        uint v0 = rowp[l];
        uint v1 = rowp[l + 64];
        acc00 = fmaf(w0, __uint_as_float(v0 << 16), acc00);
        acc01 = fmaf(w0, __uint_as_float(v0 & 0xFFFF0000u), acc01);
        acc10 = fmaf(w1, __uint_as_float(v1 << 16), acc10);
        acc11 = fmaf(w1, __uint_as_float(v1 & 0xFFFF0000u), acc11);
      }
    } else {
      for (int k = 0; k < cnt; ++k) {
        int idx = __shfl(rx, k << 3, 64);
        float w0 = __shfl(w, (k << 3) | h0, 64);
        float w1 = __shfl(w, (k << 3) | h1, 64);
        const uint* rowp = Whb_u + ((size_t)idx << 7);
        uint v0 = rowp[l];
        uint v1 = rowp[l + 64];
        acc00 = fmaf(w0, __uint_as_float(v0 << 16), acc00);
        acc01 = fmaf(w0, __uint_as_float(v0 & 0xFFFF0000u), acc01);
        acc10 = fmaf(w1, __uint_as_float(v1 << 16), acc10);
        acc11 = fmaf(w1, __uint_as_float(v1 & 0xFFFF0000u), acc11);
      }
    }
    rx = rx_n;
    s_cur = s_n;
  }

  float l0 = __shfl(l_run, h0, 64);
  float l1 = __shfl(l_run, h1, 64);
  float inv0 = (l0 > 0.f) ? 1.f / l0 : 0.f;
  float inv1 = (l1 > 0.f) ? 1.f / l1 : 0.f;
  acc00 *= inv0; acc01 *= inv0; acc10 *= inv1; acc11 *= inv1;

  float2 oA, oB;
  oA.x = acc00 > 0.f ? acc00 : expm1f(acc00);
  oA.y = acc01 > 0.f ? acc01 : expm1f(acc01);
  oB.x = acc10 > 0.f ? acc10 : expm1f(acc10);
  oB.y = acc11 > 0.f ? acc11 : expm1f(acc11);
  *(float2*)&out[(size_t)n * HF + 2 * l] = oA;
  *(float2*)&out[(size_t)n * HF + 128 + 2 * l] = oB;
}

extern "C" void kernel_launch(void* const* d_in, const int* in_sizes, int n_in,
                              void* d_out, int out_size, void* d_ws, size_t ws_size,
                              hipStream_t stream)
{
  const float* h    = (const float*)d_in[0];
  const float* ef   = (const float*)d_in[1];
  const int*   src  = (const int*)d_in[2];
  const int*   dst  = (const int*)d_in[3];
  const float* W_w  = (const float*)d_in[4];
  const float* We_w = (const float*)d_in[5];
  const float* a_s  = (const float*)d_in[6];
  const float* a_d  = (const float*)d_in[7];
  const float* a_e  = (const float*)d_in[8];
  float* out = (float*)d_out;

  char* ws = (char*)d_ws;
  size_t off = 0;
  auto take = [&](size_t bytes) {
    char* p = ws + off;
    off += (bytes + 255) & ~(size_t)255;
    return p;
  };
  ushort* Whb     = (ushort*)take((size_t)N_NODES * HF * 2);         // 25.6 MB bf16
  float* s8       = (float*)take((size_t)N_EDGES * HEADS * 4);       // 25.6 MB, EDGE order
  float* alpha_s  = (float*)take((size_t)N_NODES * HEADS * 4);
  float* alpha_d  = (float*)take((size_t)N_NODES * HEADS * 4);
  int2*  srcE     = (int2*)take((size_t)N_EDGES * 8);                // 6.4 MB
  int*   deg      = (int*)take((size_t)N_NODES * 4);
  int*   offs     = (int*)take((size_t)(N_NODES + 1) * 4);
  int*   cursor   = (int*)take((size_t)N_NODES * 4);
  float* Bmat     = (float*)take((size_t)EDGE_F * HEADS * 4);
  ushort* Wt      = (ushort*)take((size_t)HF * IN_F * 2);            // 128 KB
  int*   blockSums= (int*)take((size_t)SCAN_BLOCKS * 4);

  (void)hipMemsetAsync(deg, 0, N_NODES * sizeof(int), stream);
  k_misc<<<HIST_BLOCKS + CVTW_BLOCKS + 2, 256, 0, stream>>>(dst, deg, W_w, Wt,
                                                            We_w, a_e, Bmat);
  k_scanA<<<SCAN_BLOCKS, 256, 0, stream>>>(deg, blockSums);
  k_scanC<<<SCAN_BLOCKS, 256, 0, stream>>>(deg, blockSums, offs, cursor);
  k_gemm_fused<<<(N_NODES + 63) / 64, 256, 0, stream>>>(h, Wt, a_s, a_d, Whb,
                                                        alpha_s, alpha_d, N_NODES);
  k_sedge<<<(N_EDGES + 255) / 256, 256, 0, stream>>>(ef, src, dst, alpha_s, alpha_d,
                                                     Bmat, cursor, s8, srcE);
  k_agg<<<N_NODES / 4, 256, 0, stream>>>(s8, srcE, offs, (const uint*)Whb, out);
}

// Round 9
// 247.928 us; speedup vs baseline: 2.2955x; 1.1650x over previous
//
#include <hip/hip_runtime.h>

#define N_NODES 50000
#define N_EDGES 800000
#define HEADS 8
#define FOUT 32
#define HF 256   // HEADS*FOUT
#define IN_F 256
#define EDGE_F 64
#define SCAN_BLOCKS 196       // ceil(50000/256)
#define HIST_BLOCKS 3125      // 800000/256 exact
#define CVTW_BLOCKS 256       // 65536/256

typedef __attribute__((ext_vector_type(8))) short bf16x8;
typedef __attribute__((ext_vector_type(4))) float f32x4;

__device__ inline ushort f2bf(float f) {  // round-to-nearest-even f32 -> bf16
  unsigned u = __float_as_uint(f);
  unsigned r = 0x7FFFu + ((u >> 16) & 1u);
  return (ushort)((u + r) >> 16);
}

// ---------------- fused independent prep: hist | cvtW | bmat (block-range split) ----------------
__global__ __launch_bounds__(256) void k_misc(
    const int* __restrict__ dst, int* __restrict__ deg,
    const float* __restrict__ W, ushort* __restrict__ Wt,
    const float* __restrict__ We_w, const float* __restrict__ a_edge,
    float* __restrict__ Bmat)
{
  int b = blockIdx.x;
  if (b < HIST_BLOCKS) {
    int e = b * 256 + threadIdx.x;
    atomicAdd(&deg[dst[e]], 1);
  } else if (b < HIST_BLOCKS + CVTW_BLOCKS) {
    int i = (b - HIST_BLOCKS) * 256 + threadIdx.x;  // Wt[n][k] = bf16(W[k][n])
    int n = i >> 8, k = i & 255;
    Wt[i] = f2bf(W[k * HF + n]);
  } else {
    int i = (b - HIST_BLOCKS - CVTW_BLOCKS) * 256 + threadIdx.x;
    if (i < EDGE_F * HEADS) {
      int k = i >> 3, h = i & 7;
      float s = 0.f;
#pragma unroll
      for (int f = 0; f < FOUT; ++f)
        s += We_w[k * HF + h * FOUT + f] * a_edge[h * FOUT + f];
      Bmat[i] = s;   // layout [k][h]
    }
  }
}

// ---------------- fused GEMM: Whb = bf16(h @ W), alpha_s/d from f32 accs ----------------
__global__ __launch_bounds__(256) void k_gemm_fused(
    const float* __restrict__ A,     // h [M][256] f32
    const ushort* __restrict__ Wt,   // [256 n][256 k] bf16, K-contig
    const float* __restrict__ a_src, const float* __restrict__ a_dst,
    ushort* __restrict__ Whb,        // [M][256] bf16
    float* __restrict__ alpha_s, float* __restrict__ alpha_d, int M)
{
  __shared__ ushort As[64 * 40];    // stride 40 bf16 (80B): 2-way (free) bank aliasing
  __shared__ ushort Bs[256 * 40];
  const int tid = threadIdx.x;
  const int wave = tid >> 6, lane = tid & 63;
  const int m0 = blockIdx.x * 64;
  const int row16 = lane & 15;
  const int kg = lane >> 4;        // k-group 0..3 -> k offset kg*8
  f32x4 acc[4][4] = {};

  const int a_r = tid >> 2;              // 0..63
  const int a_c = (tid & 3) * 8;         // bf16 col 0,8,16,24
  const int a_row = m0 + a_r;

  for (int k0 = 0; k0 < IN_F; k0 += 32) {
    uint4 av = make_uint4(0, 0, 0, 0);
    if (a_row < M) {
      float4 f0 = *(const float4*)&A[(size_t)a_row * IN_F + k0 + a_c];
      float4 f1 = *(const float4*)&A[(size_t)a_row * IN_F + k0 + a_c + 4];
      av.x = (unsigned)f2bf(f0.x) | ((unsigned)f2bf(f0.y) << 16);
      av.y = (unsigned)f2bf(f0.z) | ((unsigned)f2bf(f0.w) << 16);
      av.z = (unsigned)f2bf(f1.x) | ((unsigned)f2bf(f1.y) << 16);
      av.w = (unsigned)f2bf(f1.z) | ((unsigned)f2bf(f1.w) << 16);
    }
    *(uint4*)&As[a_r * 40 + a_c] = av;
    const uint4* bp = (const uint4*)&Wt[(size_t)tid * IN_F + k0];
    uint4 b0 = bp[0], b1 = bp[1];
    *(uint4*)&Bs[tid * 40 + 0] = b0;
    *(uint4*)&Bs[tid * 40 + 8] = b1;
    uint4 b2 = bp[2], b3 = bp[3];
    *(uint4*)&Bs[tid * 40 + 16] = b2;
    *(uint4*)&Bs[tid * 40 + 24] = b3;
    __syncthreads();
    bf16x8 af[4], bfr[4];
#pragma unroll
    for (int mi = 0; mi < 4; ++mi)
      af[mi] = *(const bf16x8*)&As[(mi * 16 + row16) * 40 + kg * 8];
#pragma unroll
    for (int ni = 0; ni < 4; ++ni)
      bfr[ni] = *(const bf16x8*)&Bs[(wave * 64 + ni * 16 + row16) * 40 + kg * 8];
#pragma unroll
    for (int mi = 0; mi < 4; ++mi)
#pragma unroll
      for (int ni = 0; ni < 4; ++ni)
        acc[mi][ni] = __builtin_amdgcn_mfma_f32_16x16x32_bf16(af[mi], bfr[ni], acc[mi][ni], 0, 0, 0);
    __syncthreads();
  }

  float cs[4], cd[4];
#pragma unroll
  for (int ni = 0; ni < 4; ++ni) {
    int hh = 2 * wave + (ni >> 1);
    int ff = (ni & 1) * 16 + row16;
    cs[ni] = a_src[hh * FOUT + ff];
    cd[ni] = a_dst[hh * FOUT + ff];
  }
  // C/D layout (m89-verified): col = lane&15 (row16), row = kg*4 + reg
#pragma unroll
  for (int mi = 0; mi < 4; ++mi) {
#pragma unroll
    for (int r = 0; r < 4; ++r) {
      int row = m0 + mi * 16 + kg * 4 + r;
      float ps0 = acc[mi][0][r] * cs[0] + acc[mi][1][r] * cs[1];
      float ps1 = acc[mi][2][r] * cs[2] + acc[mi][3][r] * cs[3];
      float pd0 = acc[mi][0][r] * cd[0] + acc[mi][1][r] * cd[1];
      float pd1 = acc[mi][2][r] * cd[2] + acc[mi][3][r] * cd[3];
#pragma unroll
      for (int msk = 1; msk <= 8; msk <<= 1) {
        ps0 += __shfl_xor(ps0, msk, 64);
        ps1 += __shfl_xor(ps1, msk, 64);
        pd0 += __shfl_xor(pd0, msk, 64);
        pd1 += __shfl_xor(pd1, msk, 64);
      }
      if (row16 == 0 && row < M) {
        *(float2*)&alpha_s[row * 8 + 2 * wave] = make_float2(ps0, ps1);
        *(float2*)&alpha_d[row * 8 + 2 * wave] = make_float2(pd0, pd1);
      }
      if (row < M) {
#pragma unroll
        for (int ni = 0; ni < 4; ++ni)
          Whb[(size_t)row * HF + wave * 64 + ni * 16 + row16] = f2bf(acc[mi][ni][r]);
      }
    }
  }
}

// ---------------- hierarchical scan, phase A: per-block sums (coalesced) ----------------
__global__ __launch_bounds__(256) void k_scanA(const int* __restrict__ deg,
                                               int* __restrict__ blockSums)
{
  __shared__ int ws[4];
  int idx = blockIdx.x * 256 + threadIdx.x;
  int v = (idx < N_NODES) ? deg[idx] : 0;
  int s = v;
#pragma unroll
  for (int off = 32; off > 0; off >>= 1)
    s += __shfl_xor(s, off, 64);
  if ((threadIdx.x & 63) == 0) ws[threadIdx.x >> 6] = s;
  __syncthreads();
  if (threadIdx.x == 0)
    blockSums[blockIdx.x] = ws[0] + ws[1] + ws[2] + ws[3];
}

// ---------------- phase C (absorbs B): every block re-scans blockSums, then local scan ----------------
__global__ __launch_bounds__(256) void k_scanC(const int* __restrict__ deg,
                                               const int* __restrict__ blockSums,
                                               int* __restrict__ offsets,
                                               int* __restrict__ cursor)
{
  __shared__ int tmp[256];
  __shared__ int s_base;
  int t = threadIdx.x;
  int v = (t < SCAN_BLOCKS) ? blockSums[t] : 0;
  tmp[t] = v;
  __syncthreads();
  int x = v;
  for (int off = 1; off < 256; off <<= 1) {
    int y = (t >= off) ? tmp[t - off] : 0;
    __syncthreads();
    x += y;
    tmp[t] = x;
    __syncthreads();
  }
  if (t == (int)blockIdx.x) s_base = x - v;                 // exclusive prefix of this block
  if (blockIdx.x == 0 && t == 255) offsets[N_NODES] = x;    // grand total
  __syncthreads();
  int base = s_base;
  int idx = blockIdx.x * 256 + t;
  int d = (idx < N_NODES) ? deg[idx] : 0;
  tmp[t] = d;
  __syncthreads();
  int x2 = d;
  for (int off = 1; off < 256; off <<= 1) {
    int y = (t >= off) ? tmp[t - off] : 0;
    __syncthreads();
    x2 += y;
    tmp[t] = x2;
    __syncthreads();
  }
  if (idx < N_NODES) {
    int pre = base + x2 - d;
    offsets[idx] = pre;
    cursor[idx] = pre;
  }
}

// ---------------- edge logits, QUAD-SPLIT: 4 lanes/edge, contiguous 64B/lane ----------------
// Lane q of an edge-quad owns ef features [q*16, q*16+16) and, after the quad
// butterfly, heads {2q, 2q+1}. Per-wave footprint 4KB (was 16KB) -> L1-resident.
__global__ __launch_bounds__(256) void k_sedge(
    const float* __restrict__ ef, const int* __restrict__ src,
    const int* __restrict__ dst, const float* __restrict__ alpha_s,
    const float* __restrict__ alpha_d, const float* __restrict__ Bmat,
    int* __restrict__ cursor, float* __restrict__ s8,
    int2* __restrict__ srcE)
{
  __shared__ float Bs[EDGE_F * HEADS];
  for (int i = threadIdx.x; i < EDGE_F * HEADS; i += 256) Bs[i] = Bmat[i];
  __syncthreads();
  const int t = threadIdx.x;
  const int q = t & 3;                       // quad lane: feature block & head pair
  const int e = blockIdx.x * 64 + (t >> 2);  // 64 edges per block (800000 = 12500*64)
  const int sn = src[e], dn = dst[e];

  // partial 8-head dot over this lane's 16 contiguous features
  float sc[8] = {};
  const float4* efr = (const float4*)&ef[(size_t)e * EDGE_F + q * 16];
#pragma unroll
  for (int g = 0; g < 4; ++g) {
    float4 v = efr[g];
    const float* b0 = &Bs[(q * 16 + g * 4) * 8];
#pragma unroll
    for (int hh = 0; hh < 8; ++hh)
      sc[hh] += v.x * b0[hh] + v.y * b0[8 + hh] + v.z * b0[16 + hh] + v.w * b0[24 + hh];
  }
  // quad butterfly: lanes differing in bits 0,1 hold the other feature blocks
#pragma unroll
  for (int hh = 0; hh < 8; ++hh) {
    sc[hh] += __shfl_xor(sc[hh], 1, 64);
    sc[hh] += __shfl_xor(sc[hh], 2, 64);
  }
  // this lane finalizes heads {2q, 2q+1}
  float2 as = *(const float2*)&alpha_s[sn * 8 + 2 * q];
  float2 ad = *(const float2*)&alpha_d[dn * 8 + 2 * q];
  float a0 = sc[2 * q] + as.x + ad.x;
  float a1 = sc[2 * q + 1] + as.y + ad.y;
  a0 = a0 > 0.f ? a0 : 0.01f * a0;
  a1 = a1 > 0.f ? a1 : 0.01f * a1;
  *(float2*)&s8[(size_t)e * 8 + 2 * q] = make_float2(a0, a1);  // wave: 2KB contiguous
  // 8B CSR scatter, one lane per edge (L2-resident 6.4MB buffer)
  if (q == 0) {
    int p = atomicAdd(&cursor[dn], 1);
    srcE[p] = make_int2(sn, e);
  }
}

// ---------------- WAVE-PER-NODE online softmax + prefetched, unrolled bf16 gather ----------------
__global__ __launch_bounds__(256) void k_agg(
    const float* __restrict__ s8, const int2* __restrict__ srcE,
    const int* __restrict__ offsets, const uint* __restrict__ Whb_u,  // [N][128]
    float* __restrict__ out)
{
  const int n = blockIdx.x * 4 + (threadIdx.x >> 6);
  const int l = threadIdx.x & 63;
  const int beg = offsets[n], end = offsets[n + 1];
  const int h_sm = l & 7;    // softmax head
  const int es = l >> 3;     // softmax edge slot
  const int h0 = l >> 4;     // head of uint l
  const int h1 = 4 + h0;     // head of uint l+64

  float m_run = -3.0e38f, l_run = 0.f;
  float acc00 = 0.f, acc01 = 0.f, acc10 = 0.f, acc11 = 0.f;

  // prefetch chunk 0
  int rx = 0;
  float s_cur = -3.0e38f;
  if (beg + es < end) {
    int2 r = srcE[beg + es];
    rx = r.x;
    s_cur = s8[(size_t)r.y * 8 + h_sm];
  }

  for (int c0 = beg; c0 < end; c0 += 8) {
    const int cnt = min(8, end - c0);
    // issue next chunk's loads early (hidden under this chunk's compute+gather)
    int rx_n = 0;
    float s_n = -3.0e38f;
    if (c0 + 8 + es < end) {
      int2 r = srcE[c0 + 8 + es];
      rx_n = r.x;
      s_n = s8[(size_t)r.y * 8 + h_sm];
    }
    float s = s_cur;
    float mc = s;
    mc = fmaxf(mc, __shfl_xor(mc, 8, 64));
    mc = fmaxf(mc, __shfl_xor(mc, 16, 64));
    mc = fmaxf(mc, __shfl_xor(mc, 32, 64));
    float m_new = fmaxf(m_run, mc);
    float f = __expf(m_run - m_new);          // 0 on first chunk
    float w = __expf(s - m_new);              // 0 for invalid slots (s=-3e38)
    float ws = w;
    ws += __shfl_xor(ws, 8, 64);
    ws += __shfl_xor(ws, 16, 64);
    ws += __shfl_xor(ws, 32, 64);
    l_run = l_run * f + ws;
    m_run = m_new;
    float f0 = __shfl(f, h0, 64);
    float f1 = __shfl(f, h1, 64);
    acc00 *= f0; acc01 *= f0; acc10 *= f1; acc11 *= f1;
    if (cnt == 8) {
#pragma unroll
      for (int k = 0; k < 8; ++k) {
        int idx = __shfl(rx, k << 3, 64);
        float w0 = __shfl(w, (k << 3) | h0, 64);
        float w1 = __shfl(w, (k << 3) | h1, 64);
        const uint* rowp = Whb_u + ((size_t)idx << 7);
        uint v0 = rowp[l];
        uint v1 = rowp[l + 64];
        acc00 = fmaf(w0, __uint_as_float(v0 << 16), acc00);
        acc01 = fmaf(w0, __uint_as_float(v0 & 0xFFFF0000u), acc01);
        acc10 = fmaf(w1, __uint_as_float(v1 << 16), acc10);
        acc11 = fmaf(w1, __uint_as_float(v1 & 0xFFFF0000u), acc11);
      }
    } else {
      for (int k = 0; k < cnt; ++k) {
        int idx = __shfl(rx, k << 3, 64);
        float w0 = __shfl(w, (k << 3) | h0, 64);
        float w1 = __shfl(w, (k << 3) | h1, 64);
        const uint* rowp = Whb_u + ((size_t)idx << 7);
        uint v0 = rowp[l];
        uint v1 = rowp[l + 64];
        acc00 = fmaf(w0, __uint_as_float(v0 << 16), acc00);
        acc01 = fmaf(w0, __uint_as_float(v0 & 0xFFFF0000u), acc01);
        acc10 = fmaf(w1, __uint_as_float(v1 << 16), acc10);
        acc11 = fmaf(w1, __uint_as_float(v1 & 0xFFFF0000u), acc11);
      }
    }
    rx = rx_n;
    s_cur = s_n;
  }

  float l0 = __shfl(l_run, h0, 64);
  float l1 = __shfl(l_run, h1, 64);
  float inv0 = (l0 > 0.f) ? 1.f / l0 : 0.f;
  float inv1 = (l1 > 0.f) ? 1.f / l1 : 0.f;
  acc00 *= inv0; acc01 *= inv0; acc10 *= inv1; acc11 *= inv1;

  float2 oA, oB;
  oA.x = acc00 > 0.f ? acc00 : expm1f(acc00);
  oA.y = acc01 > 0.f ? acc01 : expm1f(acc01);
  oB.x = acc10 > 0.f ? acc10 : expm1f(acc10);
  oB.y = acc11 > 0.f ? acc11 : expm1f(acc11);
  *(float2*)&out[(size_t)n * HF + 2 * l] = oA;
  *(float2*)&out[(size_t)n * HF + 128 + 2 * l] = oB;
}

extern "C" void kernel_launch(void* const* d_in, const int* in_sizes, int n_in,
                              void* d_out, int out_size, void* d_ws, size_t ws_size,
                              hipStream_t stream)
{
  const float* h    = (const float*)d_in[0];
  const float* ef   = (const float*)d_in[1];
  const int*   src  = (const int*)d_in[2];
  const int*   dst  = (const int*)d_in[3];
  const float* W_w  = (const float*)d_in[4];
  const float* We_w = (const float*)d_in[5];
  const float* a_s  = (const float*)d_in[6];
  const float* a_d  = (const float*)d_in[7];
  const float* a_e  = (const float*)d_in[8];
  float* out = (float*)d_out;

  char* ws = (char*)d_ws;
  size_t off = 0;
  auto take = [&](size_t bytes) {
    char* p = ws + off;
    off += (bytes + 255) & ~(size_t)255;
    return p;
  };
  ushort* Whb     = (ushort*)take((size_t)N_NODES * HF * 2);         // 25.6 MB bf16
  float* s8       = (float*)take((size_t)N_EDGES * HEADS * 4);       // 25.6 MB, EDGE order
  float* alpha_s  = (float*)take((size_t)N_NODES * HEADS * 4);
  float* alpha_d  = (float*)take((size_t)N_NODES * HEADS * 4);
  int2*  srcE     = (int2*)take((size_t)N_EDGES * 8);                // 6.4 MB
  int*   deg      = (int*)take((size_t)N_NODES * 4);
  int*   offs     = (int*)take((size_t)(N_NODES + 1) * 4);
  int*   cursor   = (int*)take((size_t)N_NODES * 4);
  float* Bmat     = (float*)take((size_t)EDGE_F * HEADS * 4);
  ushort* Wt      = (ushort*)take((size_t)HF * IN_F * 2);            // 128 KB
  int*   blockSums= (int*)take((size_t)SCAN_BLOCKS * 4);

  (void)hipMemsetAsync(deg, 0, N_NODES * sizeof(int), stream);
  k_misc<<<HIST_BLOCKS + CVTW_BLOCKS + 2, 256, 0, stream>>>(dst, deg, W_w, Wt,
                                                            We_w, a_e, Bmat);
  k_scanA<<<SCAN_BLOCKS, 256, 0, stream>>>(deg, blockSums);
  k_scanC<<<SCAN_BLOCKS, 256, 0, stream>>>(deg, blockSums, offs, cursor);
  k_gemm_fused<<<(N_NODES + 63) / 64, 256, 0, stream>>>(h, Wt, a_s, a_d, Whb,
                                                        alpha_s, alpha_d, N_NODES);
  k_sedge<<<N_EDGES / 64, 256, 0, stream>>>(ef, src, dst, alpha_s, alpha_d,
                                            Bmat, cursor, s8, srcE);
  k_agg<<<N_NODES / 4, 256, 0, stream>>>(s8, srcE, offs, (const uint*)Whb, out);
}

// Round 10
// 242.797 us; speedup vs baseline: 2.3440x; 1.0211x over previous
//
#include <hip/hip_runtime.h>
#include <hip/hip_fp16.h>

#define N_NODES 50000
#define N_EDGES 800000
#define HEADS 8
#define FOUT 32
#define HF 256   // HEADS*FOUT
#define IN_F 256
#define EDGE_F 64
#define SCAN_BLOCKS 196       // ceil(50000/256)
#define HIST_BLOCKS 3125      // 800000/256 exact
#define CVTW_BLOCKS 256       // 65536/256

typedef __attribute__((ext_vector_type(8))) short bf16x8;
typedef __attribute__((ext_vector_type(4))) float f32x4;

__device__ inline ushort f2bf(float f) {  // round-to-nearest-even f32 -> bf16
  unsigned u = __float_as_uint(f);
  unsigned r = 0x7FFFu + ((u >> 16) & 1u);
  return (ushort)((u + r) >> 16);
}

// ---------------- fused independent prep: hist | cvtW | bmat (block-range split) ----------------
__global__ __launch_bounds__(256) void k_misc(
    const int* __restrict__ dst, int* __restrict__ deg,
    const float* __restrict__ W, ushort* __restrict__ Wt,
    const float* __restrict__ We_w, const float* __restrict__ a_edge,
    float* __restrict__ Bmat)
{
  int b = blockIdx.x;
  if (b < HIST_BLOCKS) {
    int e = b * 256 + threadIdx.x;
    atomicAdd(&deg[dst[e]], 1);
  } else if (b < HIST_BLOCKS + CVTW_BLOCKS) {
    int i = (b - HIST_BLOCKS) * 256 + threadIdx.x;  // Wt[n][k] = bf16(W[k][n])
    int n = i >> 8, k = i & 255;
    Wt[i] = f2bf(W[k * HF + n]);
  } else {
    int i = (b - HIST_BLOCKS - CVTW_BLOCKS) * 256 + threadIdx.x;
    if (i < EDGE_F * HEADS) {
      int k = i >> 3, h = i & 7;
      float s = 0.f;
#pragma unroll
      for (int f = 0; f < FOUT; ++f)
        s += We_w[k * HF + h * FOUT + f] * a_edge[h * FOUT + f];
      Bmat[i] = s;   // layout [k][h]
    }
  }
}

// ---------------- fused GEMM: Whb = bf16(h @ W), alpha_s/d from f32 accs ----------------
__global__ __launch_bounds__(256) void k_gemm_fused(
    const float* __restrict__ A,     // h [M][256] f32
    const ushort* __restrict__ Wt,   // [256 n][256 k] bf16, K-contig
    const float* __restrict__ a_src, const float* __restrict__ a_dst,
    ushort* __restrict__ Whb,        // [M][256] bf16
    float* __restrict__ alpha_s, float* __restrict__ alpha_d, int M)
{
  __shared__ ushort As[64 * 40];    // stride 40 bf16 (80B): 2-way (free) bank aliasing
  __shared__ ushort Bs[256 * 40];
  const int tid = threadIdx.x;
  const int wave = tid >> 6, lane = tid & 63;
  const int m0 = blockIdx.x * 64;
  const int row16 = lane & 15;
  const int kg = lane >> 4;        // k-group 0..3 -> k offset kg*8
  f32x4 acc[4][4] = {};

  const int a_r = tid >> 2;              // 0..63
  const int a_c = (tid & 3) * 8;         // bf16 col 0,8,16,24
  const int a_row = m0 + a_r;

  for (int k0 = 0; k0 < IN_F; k0 += 32) {
    uint4 av = make_uint4(0, 0, 0, 0);
    if (a_row < M) {
      float4 f0 = *(const float4*)&A[(size_t)a_row * IN_F + k0 + a_c];
      float4 f1 = *(const float4*)&A[(size_t)a_row * IN_F + k0 + a_c + 4];
      av.x = (unsigned)f2bf(f0.x) | ((unsigned)f2bf(f0.y) << 16);
      av.y = (unsigned)f2bf(f0.z) | ((unsigned)f2bf(f0.w) << 16);
      av.z = (unsigned)f2bf(f1.x) | ((unsigned)f2bf(f1.y) << 16);
      av.w = (unsigned)f2bf(f1.z) | ((unsigned)f2bf(f1.w) << 16);
    }
    *(uint4*)&As[a_r * 40 + a_c] = av;
    const uint4* bp = (const uint4*)&Wt[(size_t)tid * IN_F + k0];
    uint4 b0 = bp[0], b1 = bp[1];
    *(uint4*)&Bs[tid * 40 + 0] = b0;
    *(uint4*)&Bs[tid * 40 + 8] = b1;
    uint4 b2 = bp[2], b3 = bp[3];
    *(uint4*)&Bs[tid * 40 + 16] = b2;
    *(uint4*)&Bs[tid * 40 + 24] = b3;
    __syncthreads();
    bf16x8 af[4], bfr[4];
#pragma unroll
    for (int mi = 0; mi < 4; ++mi)
      af[mi] = *(const bf16x8*)&As[(mi * 16 + row16) * 40 + kg * 8];
#pragma unroll
    for (int ni = 0; ni < 4; ++ni)
      bfr[ni] = *(const bf16x8*)&Bs[(wave * 64 + ni * 16 + row16) * 40 + kg * 8];
#pragma unroll
    for (int mi = 0; mi < 4; ++mi)
#pragma unroll
      for (int ni = 0; ni < 4; ++ni)
        acc[mi][ni] = __builtin_amdgcn_mfma_f32_16x16x32_bf16(af[mi], bfr[ni], acc[mi][ni], 0, 0, 0);
    __syncthreads();
  }

  float cs[4], cd[4];
#pragma unroll
  for (int ni = 0; ni < 4; ++ni) {
    int hh = 2 * wave + (ni >> 1);
    int ff = (ni & 1) * 16 + row16;
    cs[ni] = a_src[hh * FOUT + ff];
    cd[ni] = a_dst[hh * FOUT + ff];
  }
  // C/D layout (m89-verified): col = lane&15 (row16), row = kg*4 + reg
#pragma unroll
  for (int mi = 0; mi < 4; ++mi) {
#pragma unroll
    for (int r = 0; r < 4; ++r) {
      int row = m0 + mi * 16 + kg * 4 + r;
      float ps0 = acc[mi][0][r] * cs[0] + acc[mi][1][r] * cs[1];
      float ps1 = acc[mi][2][r] * cs[2] + acc[mi][3][r] * cs[3];
      float pd0 = acc[mi][0][r] * cd[0] + acc[mi][1][r] * cd[1];
      float pd1 = acc[mi][2][r] * cd[2] + acc[mi][3][r] * cd[3];
#pragma unroll
      for (int msk = 1; msk <= 8; msk <<= 1) {
        ps0 += __shfl_xor(ps0, msk, 64);
        ps1 += __shfl_xor(ps1, msk, 64);
        pd0 += __shfl_xor(pd0, msk, 64);
        pd1 += __shfl_xor(pd1, msk, 64);
      }
      if (row16 == 0 && row < M) {
        *(float2*)&alpha_s[row * 8 + 2 * wave] = make_float2(ps0, ps1);
        *(float2*)&alpha_d[row * 8 + 2 * wave] = make_float2(pd0, pd1);
      }
      if (row < M) {
#pragma unroll
        for (int ni = 0; ni < 4; ++ni)
          Whb[(size_t)row * HF + wave * 64 + ni * 16 + row16] = f2bf(acc[mi][ni][r]);
      }
    }
  }
}

// ---------------- hierarchical scan, phase A: per-block sums (coalesced) ----------------
__global__ __launch_bounds__(256) void k_scanA(const int* __restrict__ deg,
                                               int* __restrict__ blockSums)
{
  __shared__ int ws[4];
  int idx = blockIdx.x * 256 + threadIdx.x;
  int v = (idx < N_NODES) ? deg[idx] : 0;
  int s = v;
#pragma unroll
  for (int off = 32; off > 0; off >>= 1)
    s += __shfl_xor(s, off, 64);
  if ((threadIdx.x & 63) == 0) ws[threadIdx.x >> 6] = s;
  __syncthreads();
  if (threadIdx.x == 0)
    blockSums[blockIdx.x] = ws[0] + ws[1] + ws[2] + ws[3];
}

// ---------------- phase C (absorbs B): every block re-scans blockSums, then local scan ----------------
__global__ __launch_bounds__(256) void k_scanC(const int* __restrict__ deg,
                                               const int* __restrict__ blockSums,
                                               int* __restrict__ offsets,
                                               int* __restrict__ cursor)
{
  __shared__ int tmp[256];
  __shared__ int s_base;
  int t = threadIdx.x;
  int v = (t < SCAN_BLOCKS) ? blockSums[t] : 0;
  tmp[t] = v;
  __syncthreads();
  int x = v;
  for (int off = 1; off < 256; off <<= 1) {
    int y = (t >= off) ? tmp[t - off] : 0;
    __syncthreads();
    x += y;
    tmp[t] = x;
    __syncthreads();
  }
  if (t == (int)blockIdx.x) s_base = x - v;                 // exclusive prefix of this block
  if (blockIdx.x == 0 && t == 255) offsets[N_NODES] = x;    // grand total
  __syncthreads();
  int base = s_base;
  int idx = blockIdx.x * 256 + t;
  int d = (idx < N_NODES) ? deg[idx] : 0;
  tmp[t] = d;
  __syncthreads();
  int x2 = d;
  for (int off = 1; off < 256; off <<= 1) {
    int y = (t >= off) ? tmp[t - off] : 0;
    __syncthreads();
    x2 += y;
    tmp[t] = x2;
    __syncthreads();
  }
  if (idx < N_NODES) {
    int pre = base + x2 - d;
    offsets[idx] = pre;
    cursor[idx] = pre;
  }
}

// ---------------- edge logits, QUAD-SPLIT, scattered to CSR order as fp16 ----------------
// Lane q owns ef features [q*16,q*16+16) and heads {2q,2q+1}. Record = 8 fp16 (16B),
// written by the quad as 4 uints at p*16B. Randomness lives on the STORE side
// (no wave stall); k_agg's reads become fully coalesced.
__global__ __launch_bounds__(256) void k_sedge(
    const float* __restrict__ ef, const int* __restrict__ src,
    const int* __restrict__ dst, const float* __restrict__ alpha_s,
    const float* __restrict__ alpha_d, const float* __restrict__ Bmat,
    int* __restrict__ cursor, uint* __restrict__ s16u,
    int* __restrict__ srcN)
{
  __shared__ float Bs[EDGE_F * HEADS];
  for (int i = threadIdx.x; i < EDGE_F * HEADS; i += 256) Bs[i] = Bmat[i];
  __syncthreads();
  const int t = threadIdx.x;
  const int q = t & 3;                       // quad lane: feature block & head pair
  const int e = blockIdx.x * 64 + (t >> 2);  // 64 edges per block (800000 = 12500*64)
  const int sn = src[e], dn = dst[e];

  // partial 8-head dot over this lane's 16 contiguous features
  float sc[8] = {};
  const float4* efr = (const float4*)&ef[(size_t)e * EDGE_F + q * 16];
#pragma unroll
  for (int g = 0; g < 4; ++g) {
    float4 v = efr[g];
    const float* b0 = &Bs[(q * 16 + g * 4) * 8];
#pragma unroll
    for (int hh = 0; hh < 8; ++hh)
      sc[hh] += v.x * b0[hh] + v.y * b0[8 + hh] + v.z * b0[16 + hh] + v.w * b0[24 + hh];
  }
  // quad butterfly: lanes differing in bits 0,1 hold the other feature blocks
#pragma unroll
  for (int hh = 0; hh < 8; ++hh) {
    sc[hh] += __shfl_xor(sc[hh], 1, 64);
    sc[hh] += __shfl_xor(sc[hh], 2, 64);
  }
  // this lane finalizes heads {2q, 2q+1}
  float2 as = *(const float2*)&alpha_s[sn * 8 + 2 * q];
  float2 ad = *(const float2*)&alpha_d[dn * 8 + 2 * q];
  float a0 = sc[2 * q] + as.x + ad.x;
  float a1 = sc[2 * q + 1] + as.y + ad.y;
  a0 = a0 > 0.f ? a0 : 0.01f * a0;
  a1 = a1 > 0.f ? a1 : 0.01f * a1;
  // pack to fp16 pair (|s| ~ few units -> abs err ~1e-3, safe)
  uint hv = (uint)__half_as_ushort(__float2half_rn(a0)) |
            ((uint)__half_as_ushort(__float2half_rn(a1)) << 16);
  // CSR slot from one atomic per edge, broadcast to the quad
  int p = 0;
  if (q == 0) p = atomicAdd(&cursor[dn], 1);
  p = __shfl(p, t & 60, 64);                 // quad-base lane
  s16u[(size_t)p * 4 + q] = hv;              // quad writes 16B record
  if (q == 0) srcN[p] = sn;                  // 4B scatter, L2-resident
}

// ---------------- WAVE-PER-NODE online softmax (coalesced fp16 logits) + bf16 gather ----------------
__global__ __launch_bounds__(256) void k_agg(
    const ushort* __restrict__ s16, const int* __restrict__ srcN,
    const int* __restrict__ offsets, const uint* __restrict__ Whb_u,  // [N][128]
    float* __restrict__ out)
{
  const int n = blockIdx.x * 4 + (threadIdx.x >> 6);
  const int l = threadIdx.x & 63;
  const int beg = offsets[n], end = offsets[n + 1];
  const int es = l >> 3;     // softmax edge slot (l = es*8 + h_sm matches record layout)
  const int h0 = l >> 4;     // head of uint l
  const int h1 = 4 + h0;     // head of uint l+64

  float m_run = -3.0e38f, l_run = 0.f;
  float acc00 = 0.f, acc01 = 0.f, acc10 = 0.f, acc11 = 0.f;

  // prefetch chunk 0 (both loads COALESCED: s16 is 128B/wave contiguous)
  int rx = 0;
  float s_cur = -3.0e38f;
  if (beg + es < end) {
    rx = srcN[beg + es];
    s_cur = __half2float(((const __half*)s16)[(size_t)beg * 8 + l]);
  }

  for (int c0 = beg; c0 < end; c0 += 8) {
    const int cnt = min(8, end - c0);
    // issue next chunk's loads early
    int rx_n = 0;
    float s_n = -3.0e38f;
    if (c0 + 8 + es < end) {
      rx_n = srcN[c0 + 8 + es];
      s_n = __half2float(((const __half*)s16)[(size_t)(c0 + 8) * 8 + l]);
    }
    float s = s_cur;
    float mc = s;
    mc = fmaxf(mc, __shfl_xor(mc, 8, 64));
    mc = fmaxf(mc, __shfl_xor(mc, 16, 64));
    mc = fmaxf(mc, __shfl_xor(mc, 32, 64));
    float m_new = fmaxf(m_run, mc);
    float f = __expf(m_run - m_new);          // 0 on first chunk
    float w = __expf(s - m_new);              // 0 for invalid slots (s=-3e38)
    float ws = w;
    ws += __shfl_xor(ws, 8, 64);
    ws += __shfl_xor(ws, 16, 64);
    ws += __shfl_xor(ws, 32, 64);
    l_run = l_run * f + ws;
    m_run = m_new;
    float f0 = __shfl(f, h0, 64);
    float f1 = __shfl(f, h1, 64);
    acc00 *= f0; acc01 *= f0; acc10 *= f1; acc11 *= f1;
    if (cnt == 8) {
#pragma unroll
      for (int k = 0; k < 8; ++k) {
        int idx = __shfl(rx, k << 3, 64);
        float w0 = __shfl(w, (k << 3) | h0, 64);
        float w1 = __shfl(w, (k << 3) | h1, 64);
        const uint* rowp = Whb_u + ((size_t)idx << 7);
        uint v0 = rowp[l];
        uint v1 = rowp[l + 64];
        acc00 = fmaf(w0, __uint_as_float(v0 << 16), acc00);
        acc01 = fmaf(w0, __uint_as_float(v0 & 0xFFFF0000u), acc01);
        acc10 = fmaf(w1, __uint_as_float(v1 << 16), acc10);
        acc11 = fmaf(w1, __uint_as_float(v1 & 0xFFFF0000u), acc11);
      }
    } else {
      for (int k = 0; k < cnt; ++k) {
        int idx = __shfl(rx, k << 3, 64);
        float w0 = __shfl(w, (k << 3) | h0, 64);
        float w1 = __shfl(w, (k << 3) | h1, 64);
        const uint* rowp = Whb_u + ((size_t)idx << 7);
        uint v0 = rowp[l];
        uint v1 = rowp[l + 64];
        acc00 = fmaf(w0, __uint_as_float(v0 << 16), acc00);
        acc01 = fmaf(w0, __uint_as_float(v0 & 0xFFFF0000u), acc01);
        acc10 = fmaf(w1, __uint_as_float(v1 << 16), acc10);
        acc11 = fmaf(w1, __uint_as_float(v1 & 0xFFFF0000u), acc11);
      }
    }
    rx = rx_n;
    s_cur = s_n;
  }

  float l0 = __shfl(l_run, h0, 64);
  float l1 = __shfl(l_run, h1, 64);
  float inv0 = (l0 > 0.f) ? 1.f / l0 : 0.f;
  float inv1 = (l1 > 0.f) ? 1.f / l1 : 0.f;
  acc00 *= inv0; acc01 *= inv0; acc10 *= inv1; acc11 *= inv1;

  float2 oA, oB;
  oA.x = acc00 > 0.f ? acc00 : expm1f(acc00);
  oA.y = acc01 > 0.f ? acc01 : expm1f(acc01);
  oB.x = acc10 > 0.f ? acc10 : expm1f(acc10);
  oB.y = acc11 > 0.f ? acc11 : expm1f(acc11);
  *(float2*)&out[(size_t)n * HF + 2 * l] = oA;
  *(float2*)&out[(size_t)n * HF + 128 + 2 * l] = oB;
}

extern "C" void kernel_launch(void* const* d_in, const int* in_sizes, int n_in,
                              void* d_out, int out_size, void* d_ws, size_t ws_size,
                              hipStream_t stream)
{
  const float* h    = (const float*)d_in[0];
  const float* ef   = (const float*)d_in[1];
  const int*   src  = (const int*)d_in[2];
  const int*   dst  = (const int*)d_in[3];
  const float* W_w  = (const float*)d_in[4];
  const float* We_w = (const float*)d_in[5];
  const float* a_s  = (const float*)d_in[6];
  const float* a_d  = (const float*)d_in[7];
  const float* a_e  = (const float*)d_in[8];
  float* out = (float*)d_out;

  char* ws = (char*)d_ws;
  size_t off = 0;
  auto take = [&](size_t bytes) {
    char* p = ws + off;
    off += (bytes + 255) & ~(size_t)255;
    return p;
  };
  ushort* Whb     = (ushort*)take((size_t)N_NODES * HF * 2);         // 25.6 MB bf16
  uint*   s16u    = (uint*)take((size_t)N_EDGES * 8 * 2);            // 12.8 MB fp16, CSR order
  float* alpha_s  = (float*)take((size_t)N_NODES * HEADS * 4);
  float* alpha_d  = (float*)take((size_t)N_NODES * HEADS * 4);
  int*   srcN     = (int*)take((size_t)N_EDGES * 4);                 // 3.2 MB
  int*   deg      = (int*)take((size_t)N_NODES * 4);
  int*   offs     = (int*)take((size_t)(N_NODES + 1) * 4);
  int*   cursor   = (int*)take((size_t)N_NODES * 4);
  float* Bmat     = (float*)take((size_t)EDGE_F * HEADS * 4);
  ushort* Wt      = (ushort*)take((size_t)HF * IN_F * 2);            // 128 KB
  int*   blockSums= (int*)take((size_t)SCAN_BLOCKS * 4);

  (void)hipMemsetAsync(deg, 0, N_NODES * sizeof(int), stream);
  k_misc<<<HIST_BLOCKS + CVTW_BLOCKS + 2, 256, 0, stream>>>(dst, deg, W_w, Wt,
                                                            We_w, a_e, Bmat);
  k_scanA<<<SCAN_BLOCKS, 256, 0, stream>>>(deg, blockSums);
  k_scanC<<<SCAN_BLOCKS, 256, 0, stream>>>(deg, blockSums, offs, cursor);
  k_gemm_fused<<<(N_NODES + 63) / 64, 256, 0, stream>>>(h, Wt, a_s, a_d, Whb,
                                                        alpha_s, alpha_d, N_NODES);
  k_sedge<<<N_EDGES / 64, 256, 0, stream>>>(ef, src, dst, alpha_s, alpha_d,
                                            Bmat, cursor, s16u, srcN);
  k_agg<<<N_NODES / 4, 256, 0, stream>>>((const ushort*)s16u, srcN, offs,
                                         (const uint*)Whb, out);
}